// Round 1
// baseline (580.523 us; speedup 1.0000x reference)
//
#include <hip/hip_runtime.h>

#define B_ 4
#define T_ 1024
#define HID_ 1024
#define H_ 8
#define CONV_DIM_ 3072
#define MROWS (B_*T_)

typedef __bf16 bf16x8 __attribute__((ext_vector_type(8)));
typedef float f32x4 __attribute__((ext_vector_type(4)));

static __device__ __forceinline__ unsigned short f2bf(float f) {
  unsigned u = __float_as_uint(f);
  unsigned r = u + 0x7fffu + ((u >> 16) & 1u);   // RNE
  return (unsigned short)(r >> 16);
}
static __device__ __forceinline__ float bfu2f(unsigned short v) {
  return __uint_as_float(((unsigned)v) << 16);
}

// async global->LDS 16B. LDS dest must be wave-uniform base + lane*16 (m104/m108).
static __device__ __forceinline__ void gld16(void* lds, const void* g) {
  __builtin_amdgcn_global_load_lds(
      (const __attribute__((address_space(1))) unsigned int*)g,
      (__attribute__((address_space(3))) unsigned int*)lds, 16, 0, 0);
}

// fp32 -> bf16 elementwise
__global__ __launch_bounds__(256) void f2bf_kernel(
    const float* __restrict__ src, unsigned short* __restrict__ dst, int n) {
  int i = (blockIdx.x * 256 + threadIdx.x) * 4;
  if (i >= n) return;
  float4 v = *(const float4*)(src + i);
  ushort4 o;
  o.x = f2bf(v.x); o.y = f2bf(v.y); o.z = f2bf(v.z); o.w = f2bf(v.w);
  *(ushort4*)(dst + i) = o;
}

// fp32 -> (hi, lo) bf16 split
__global__ __launch_bounds__(256) void f2bf_split_kernel(
    const float* __restrict__ src, unsigned short* __restrict__ hi,
    unsigned short* __restrict__ lo, int n) {
  int i = (blockIdx.x * 256 + threadIdx.x) * 4;
  if (i >= n) return;
  float4 v = *(const float4*)(src + i);
  ushort4 h, l;
  h.x = f2bf(v.x); h.y = f2bf(v.y); h.z = f2bf(v.z); h.w = f2bf(v.w);
  l.x = f2bf(v.x - bfu2f(h.x));
  l.y = f2bf(v.y - bfu2f(h.y));
  l.z = f2bf(v.z - bfu2f(h.z));
  l.w = f2bf(v.w - bfu2f(h.w));
  *(ushort4*)(hi + i) = h;
  *(ushort4*)(lo + i) = l;
}

// Single-pass bf16 MFMA GEMM: C[M,N] = A[M,K] * W[N,K]^T. 128x128 tile, BK=32.
// Staging via global_load_lds (async direct-to-LDS).
template<int OUT_BF16>
__global__ __launch_bounds__(256) void gemm_mfma_kernel(
    const unsigned short* __restrict__ A, const unsigned short* __restrict__ W,
    void* __restrict__ Cv, int M, int N, int K) {
  __shared__ __align__(16) unsigned short lA[128*32];
  __shared__ __align__(16) unsigned short lB[128*32];
  const int tid  = threadIdx.x;
  const int lane = tid & 63;
  const int wv   = tid >> 6;
  const int wm   = (wv >> 1) * 64;
  const int wn   = (wv & 1) * 64;
  const int m16  = lane & 15;
  const int quad = lane >> 4;
  const int bm = blockIdx.y * 128;
  const int bn = blockIdx.x * 128;

  f32x4 acc[4][4];
  #pragma unroll
  for (int i = 0; i < 4; ++i)
    #pragma unroll
    for (int j = 0; j < 4; ++j)
      acc[i][j] = (f32x4){0.f, 0.f, 0.f, 0.f};

  const int r0 = tid >> 2, c0 = tid & 3;
  const int r1 = r0 + 64;
  const int g0 = (c0 ^ (r0 & 3)) * 8;
  const int g1 = (c0 ^ (r1 & 3)) * 8;
  const unsigned short* Ar0 = A + (size_t)(bm + r0) * K + g0;
  const unsigned short* Ar1 = A + (size_t)(bm + r1) * K + g1;
  const unsigned short* Wr0 = W + (size_t)(bn + r0) * K + g0;
  const unsigned short* Wr1 = W + (size_t)(bn + r1) * K + g1;
  unsigned short* sA0 = &lA[(size_t)tid * 8];        // byte off = wv*1024 + lane*16
  unsigned short* sA1 = &lA[(size_t)(tid + 256) * 8];
  unsigned short* sB0 = &lB[(size_t)tid * 8];
  unsigned short* sB1 = &lB[(size_t)(tid + 256) * 8];

  int offA[4], offB[4];
  #pragma unroll
  for (int i = 0; i < 4; ++i) {
    int ra = wm + i * 16 + m16;
    offA[i] = ra * 32 + (quad ^ (ra & 3)) * 8;
    int rb = wn + i * 16 + m16;
    offB[i] = rb * 32 + (quad ^ (rb & 3)) * 8;
  }

  for (int k0 = 0; k0 < K; k0 += 32) {
    gld16(sA0, Ar0 + k0);
    gld16(sA1, Ar1 + k0);
    gld16(sB0, Wr0 + k0);
    gld16(sB1, Wr1 + k0);
    __syncthreads();    // drains vmcnt (incl. global_load_lds)
    bf16x8 af[4], bfr[4];
    #pragma unroll
    for (int i = 0; i < 4; ++i) {
      af[i]  = *(const bf16x8*)&lA[offA[i]];
      bfr[i] = *(const bf16x8*)&lB[offB[i]];
    }
    #pragma unroll
    for (int mi = 0; mi < 4; ++mi)
      #pragma unroll
      for (int ni = 0; ni < 4; ++ni)
        acc[mi][ni] = __builtin_amdgcn_mfma_f32_16x16x32_bf16(af[mi], bfr[ni], acc[mi][ni], 0, 0, 0);
    __syncthreads();
  }

  #pragma unroll
  for (int mi = 0; mi < 4; ++mi) {
    #pragma unroll
    for (int r = 0; r < 4; ++r) {
      size_t row = (size_t)(bm + wm + mi * 16 + quad * 4 + r);
      #pragma unroll
      for (int ni = 0; ni < 4; ++ni) {
        int col = bn + wn + ni * 16 + m16;
        float val = acc[mi][ni][r];
        if (OUT_BF16) ((unsigned short*)Cv)[row * N + col] = f2bf(val);
        else          ((float*)Cv)[row * N + col] = val;
      }
    }
  }
}

// Split-precision MFMA GEMM: C ~= Ahi*Whi + Ahi*Wlo + Alo*Whi. fp32 out.
// Staging via global_load_lds.
__global__ __launch_bounds__(256) void gemm_mfma_split_kernel(
    const unsigned short* __restrict__ Ahi, const unsigned short* __restrict__ Alo,
    const unsigned short* __restrict__ Whi, const unsigned short* __restrict__ Wlo,
    float* __restrict__ C, int M, int N, int K) {
  __shared__ __align__(16) unsigned short lAh[128*32];
  __shared__ __align__(16) unsigned short lAl[128*32];
  __shared__ __align__(16) unsigned short lBh[128*32];
  __shared__ __align__(16) unsigned short lBl[128*32];
  const int tid  = threadIdx.x;
  const int lane = tid & 63;
  const int wv   = tid >> 6;
  const int wm   = (wv >> 1) * 64;
  const int wn   = (wv & 1) * 64;
  const int m16  = lane & 15;
  const int quad = lane >> 4;
  const int bm = blockIdx.y * 128;
  const int bn = blockIdx.x * 128;

  f32x4 acc[4][4];
  #pragma unroll
  for (int i = 0; i < 4; ++i)
    #pragma unroll
    for (int j = 0; j < 4; ++j)
      acc[i][j] = (f32x4){0.f, 0.f, 0.f, 0.f};

  const int r0 = tid >> 2, c0 = tid & 3;
  const int r1 = r0 + 64;
  const int g0 = (c0 ^ (r0 & 3)) * 8;
  const int g1 = (c0 ^ (r1 & 3)) * 8;
  const size_t oA0 = (size_t)(bm + r0) * K + g0;
  const size_t oA1 = (size_t)(bm + r1) * K + g1;
  const size_t oB0 = (size_t)(bn + r0) * K + g0;
  const size_t oB1 = (size_t)(bn + r1) * K + g1;
  const int s0 = tid * 8, s1 = (tid + 256) * 8;

  int offA[4], offB[4];
  #pragma unroll
  for (int i = 0; i < 4; ++i) {
    int ra = wm + i * 16 + m16;
    offA[i] = ra * 32 + (quad ^ (ra & 3)) * 8;
    int rb = wn + i * 16 + m16;
    offB[i] = rb * 32 + (quad ^ (rb & 3)) * 8;
  }

  for (int k0 = 0; k0 < K; k0 += 32) {
    gld16(&lAh[s0], Ahi + oA0 + k0);
    gld16(&lAh[s1], Ahi + oA1 + k0);
    gld16(&lAl[s0], Alo + oA0 + k0);
    gld16(&lAl[s1], Alo + oA1 + k0);
    gld16(&lBh[s0], Whi + oB0 + k0);
    gld16(&lBh[s1], Whi + oB1 + k0);
    gld16(&lBl[s0], Wlo + oB0 + k0);
    gld16(&lBl[s1], Wlo + oB1 + k0);
    __syncthreads();
    bf16x8 afh[4], bfh[4];
    #pragma unroll
    for (int i = 0; i < 4; ++i) {
      afh[i] = *(const bf16x8*)&lAh[offA[i]];
      bfh[i] = *(const bf16x8*)&lBh[offB[i]];
    }
    #pragma unroll
    for (int mi = 0; mi < 4; ++mi)
      #pragma unroll
      for (int ni = 0; ni < 4; ++ni)
        acc[mi][ni] = __builtin_amdgcn_mfma_f32_16x16x32_bf16(afh[mi], bfh[ni], acc[mi][ni], 0, 0, 0);
    {
      bf16x8 bfl[4];
      #pragma unroll
      for (int i = 0; i < 4; ++i) bfl[i] = *(const bf16x8*)&lBl[offB[i]];
      #pragma unroll
      for (int mi = 0; mi < 4; ++mi)
        #pragma unroll
        for (int ni = 0; ni < 4; ++ni)
          acc[mi][ni] = __builtin_amdgcn_mfma_f32_16x16x32_bf16(afh[mi], bfl[ni], acc[mi][ni], 0, 0, 0);
    }
    {
      bf16x8 afl[4];
      #pragma unroll
      for (int i = 0; i < 4; ++i) afl[i] = *(const bf16x8*)&lAl[offA[i]];
      #pragma unroll
      for (int mi = 0; mi < 4; ++mi)
        #pragma unroll
        for (int ni = 0; ni < 4; ++ni)
          acc[mi][ni] = __builtin_amdgcn_mfma_f32_16x16x32_bf16(afl[mi], bfh[ni], acc[mi][ni], 0, 0, 0);
    }
    __syncthreads();
  }

  #pragma unroll
  for (int mi = 0; mi < 4; ++mi) {
    #pragma unroll
    for (int r = 0; r < 4; ++r) {
      size_t row = (size_t)(bm + wm + mi * 16 + quad * 4 + r);
      #pragma unroll
      for (int ni = 0; ni < 4; ++ni)
        C[row * N + bn + wn + ni * 16 + m16] = acc[mi][ni][r];
    }
  }
}

// bb/aa projections fused with beta / g=log(alpha). Reads fp32 hs (exact).
__global__ __launch_bounds__(128) void proj_ba_kernel(
    const float* __restrict__ hs, const float* __restrict__ b_w, const float* __restrict__ a_w,
    const float* __restrict__ dt_bias, const float* __restrict__ A_log,
    float* __restrict__ gout, float* __restrict__ beta) {
  const int bt = blockIdx.x;
  const int b = bt >> 10;
  const int t = bt & 1023;
  const int tid = threadIdx.x;
  const int grp = tid >> 3;
  const int l8 = tid & 7;
  const int h = grp & 7;
  const bool isA = grp >= 8;
  const float* w = (isA ? a_w : b_w) + (size_t)h * HID_;
  const float* x = hs + (size_t)bt * HID_;
  float s = 0.f;
  for (int e = l8*4; e < HID_; e += 32){
    float4 xv = *(const float4*)(x + e);
    float4 wv = *(const float4*)(w + e);
    s = fmaf(xv.x, wv.x, s);
    s = fmaf(xv.y, wv.y, s);
    s = fmaf(xv.z, wv.z, s);
    s = fmaf(xv.w, wv.w, s);
  }
  s += __shfl_xor(s,1); s += __shfl_xor(s,2); s += __shfl_xor(s,4);
  if (l8 == 0) {
    size_t o = ((size_t)(b*H_ + h))*T_ + t;
    if (!isA) {
      beta[o] = 1.f/(1.f+expf(-s));
    } else {
      float xx = s + dt_bias[h];
      float sp = fmaxf(xx,0.f) + log1pf(expf(-fabsf(xx)));   // softplus
      gout[o] = -expf(A_log[h]) * sp;                        // g = log(alpha)
    }
  }
}

// causal depthwise conv (K=4), 4 t-steps per thread (7 loads -> 4 outputs)
__global__ __launch_bounds__(256) void conv_route_kernel(
    const float* __restrict__ mixed, const float* __restrict__ conv_w,
    float* __restrict__ qb, float* __restrict__ kb, float* __restrict__ vb) {
  const int idx = blockIdx.x*256 + threadIdx.x;
  const int c = idx % CONV_DIM_;
  const int bt4 = idx / CONV_DIM_;
  const int b = bt4 >> 8;            // T/4 = 256 groups
  const int t0 = (bt4 & 255) * 4;
  float w0=conv_w[c*4],w1=conv_w[c*4+1],w2=conv_w[c*4+2],w3=conv_w[c*4+3];
  float x[7];
  #pragma unroll
  for (int j=0;j<7;++j){
    int tt = t0 - 3 + j;
    x[j] = (tt >= 0) ? mixed[((size_t)(b*T_+tt))*CONV_DIM_ + c] : 0.f;
  }
  const int part = c >> 10;
  const int cc = c & 1023;
  const int hh = cc >> 7;
  const int d = cc & 127;
  float* dst = part==0 ? qb : (part==1 ? kb : vb);
  size_t base = (((size_t)(b*H_+hh))*T_ + t0)*128 + d;
  #pragma unroll
  for (int i=0;i<4;++i){
    float s = fmaf(w0,x[i],fmaf(w1,x[i+1],fmaf(w2,x[i+2],w3*x[i+3])));
    dst[base + (size_t)i*128] = s;
  }
}

// Parallel precompute: 512 blocks = (bh, chunk).
// T = (I+A)^-1 (unit lower), B = incl-lower decayed QK^T.
__global__ __launch_bounds__(256) void scan_ab_kernel(
    const float* __restrict__ qb, const float* __restrict__ kb,
    const float* __restrict__ gbuf, const float* __restrict__ bbuf,
    float* __restrict__ Tg, float* __restrict__ Bg) {
  const int blk = blockIdx.x;
  const int bh = blk >> 4;
  const int ch = blk & 15;
  const int t0 = ch * 64;
  const int tid = threadIdx.x;
  __shared__ float sK[64][132];
  __shared__ float sAA[64][68];
  __shared__ float lL[64];
  __shared__ float bL[64];
  const float* kg = kb + (size_t)bh*T_*128;
  const float* qg = qb + (size_t)bh*T_*128;
  float* To = Tg + (size_t)blk*4096;
  float* Bo = Bg + (size_t)blk*4096;

  #pragma unroll
  for (int i = 0; i < 8; ++i) {
    int f4 = tid + 256*i;
    int row = f4 >> 5, c = f4 & 31;
    *(float4*)&sK[row][c*4] = *(const float4*)(kg + (size_t)(t0+row)*128 + c*4);
  }
  if (tid < 64) {
    float x = gbuf[(size_t)bh*T_ + t0 + tid];
    #pragma unroll
    for (int o = 1; o < 64; o <<= 1) {
      float y = __shfl_up(x, o);
      if (tid >= o) x += y;
    }
    lL[tid] = x;
    bL[tid] = bbuf[(size_t)bh*T_ + t0 + tid];
  }
  __syncthreads();

  const int it = tid >> 4, jt = tid & 15;
  {
    float acc[4][4] = {};
    if (jt <= it) {
      for (int kk = 0; kk < 128; kk += 4) {
        float4 ka[4], kc[4];
        #pragma unroll
        for (int r = 0; r < 4; ++r) {
          ka[r] = *(const float4*)&sK[it*4+r][kk];
          kc[r] = *(const float4*)&sK[jt*4+r][kk];
        }
        #pragma unroll
        for (int a = 0; a < 4; ++a)
          #pragma unroll
          for (int b = 0; b < 4; ++b) {
            acc[a][b] = fmaf(ka[a].x, kc[b].x, acc[a][b]);
            acc[a][b] = fmaf(ka[a].y, kc[b].y, acc[a][b]);
            acc[a][b] = fmaf(ka[a].z, kc[b].z, acc[a][b]);
            acc[a][b] = fmaf(ka[a].w, kc[b].w, acc[a][b]);
          }
      }
    }
    #pragma unroll
    for (int a = 0; a < 4; ++a) {
      int i = it*4 + a;
      float bi = bL[i], li = lL[i];
      #pragma unroll
      for (int b = 0; b < 4; ++b) {
        int j = jt*4 + b;
        sAA[i][j] = (j < i) ? bi * __expf(li - lL[j]) * acc[a][b] : 0.f;
      }
    }
  }
  {
    float acc[4][4] = {};
    if (jt <= it) {
      for (int kk = 0; kk < 128; kk += 4) {
        float4 qa[4], kc[4];
        #pragma unroll
        for (int r = 0; r < 4; ++r) {
          qa[r] = *(const float4*)(qg + (size_t)(t0+it*4+r)*128 + kk);
          kc[r] = *(const float4*)&sK[jt*4+r][kk];
        }
        #pragma unroll
        for (int a = 0; a < 4; ++a)
          #pragma unroll
          for (int b = 0; b < 4; ++b) {
            acc[a][b] = fmaf(qa[a].x, kc[b].x, acc[a][b]);
            acc[a][b] = fmaf(qa[a].y, kc[b].y, acc[a][b]);
            acc[a][b] = fmaf(qa[a].z, kc[b].z, acc[a][b]);
            acc[a][b] = fmaf(qa[a].w, kc[b].w, acc[a][b]);
          }
      }
    }
    #pragma unroll
    for (int a = 0; a < 4; ++a) {
      int i = it*4 + a;
      float li = lL[i];
      #pragma unroll
      for (int b = 0; b < 4; ++b) {
        int j = jt*4 + b;
        Bo[i*64 + j] = (j <= i) ? __expf(li - lL[j]) * acc[a][b] : 0.f;
      }
    }
  }
  __syncthreads();

  // invert (I+A): 4 waves x 16 cols, rows rr+4m per thread; wave-local chain
  {
    const int w = tid >> 6;
    const int ln = tid & 63;
    const int colc = w*16 + (ln & 15);
    const int rr = ln >> 4;
    float rh[16];
    #pragma unroll
    for (int m=0;m<16;++m) rh[m] = (rr + 4*m == colc) ? 1.f : 0.f;
    for (int j = 0; j < 63; ++j) {
      int src = ((j & 3) << 4) | (ln & 15);
      float wj = __shfl(rh[j >> 2], src);
      #pragma unroll
      for (int m=0;m<16;++m)
        rh[m] = fmaf(-sAA[rr + 4*m][j], wj, rh[m]);
    }
    #pragma unroll
    for (int m=0;m<16;++m)
      To[(rr + 4*m)*64 + colc] = rh[m];
  }
}

// Sequential chunked scan, 512 threads (8 waves), UT-transform form.
// 256 blocks = 32 bh x 8 dv-slices(16).
// Re-tiled for LDS-read throughput (the measured bottleneck):
//  F: 2 rows (K+Q share S0 reads) x 4 cols, 4-way interleaved k-split
//  W/O: 2 rows x 4 cols, 4-way j-split; U: 4 vcols x 4 k, 4-way j-split.
//  All reductions are shfl_xor(1)/(2) only (DPP). qs held in registers F->O.
//  sW/sW2 stride 24 (20 gives 3-way bank conflicts under the j-split).
__global__ __launch_bounds__(512) void scan_seq_kernel(
    const float* __restrict__ qb, const float* __restrict__ kb, const float* __restrict__ vb,
    const float* __restrict__ gbuf, const float* __restrict__ bbuf,
    const float* __restrict__ Tg, const float* __restrict__ Bg,
    float* __restrict__ ob) {
  const int bh = blockIdx.x >> 3;
  const int sl = blockIdx.x & 7;
  const int tid = threadIdx.x;

  __shared__ float sK[64][132];
  __shared__ float sQ[64][132];
  __shared__ float sT[64][68];
  __shared__ float sBB[64][68];
  __shared__ float sS0T[16][132];   // state transposed: [vcol][k]
  __shared__ float sW[64][24];      // RHS
  __shared__ float sW2[64][24];     // W = T*RHS
  __shared__ float sW3T[16][68];    // W scaled, transposed [col][row] for U phase
  __shared__ float lL[64];
  __shared__ float bL[64];
  // total static LDS = 128000 B (known-good <= 131072)

  const float* kg = kb + (size_t)bh*T_*128;
  const float* qg = qb + (size_t)bh*T_*128;
  const float* vg = vb + (size_t)bh*T_*128 + sl*16;
  const float* gg = gbuf + (size_t)bh*T_;
  const float* beg = bbuf + (size_t)bh*T_;
  float* og = ob + (size_t)bh*T_*128 + sl*16;

  const int ls  = tid & 3;               // 4-way reduction split (k in F, j in W/O/U)
  const int cg4 = ((tid >> 2) & 3) * 4;  // col group (F/W/O) / v group (U)
  const int rg  = tid >> 4;              // 0..31: row pair (F/W/O) / k-quad (U)

  for (int z = tid; z < 16*132; z += 512) ((float*)sS0T)[z] = 0.f;

#define DOT4(acc, a, b) acc = fmaf((a).x,(b).x,fmaf((a).y,(b).y,fmaf((a).z,(b).z,fmaf((a).w,(b).w,acc))))
#define FMA4(acc, v4, s) acc.x = fmaf((v4).x,(s),acc.x); acc.y = fmaf((v4).y,(s),acc.y); \
                         acc.z = fmaf((v4).z,(s),acc.z); acc.w = fmaf((v4).w,(s),acc.w);
#define RED2(x) x += __shfl_xor(x,1); x += __shfl_xor(x,2);

  for (int ch = 0; ch < 16; ++ch) {
    const int t0 = ch * 64;
    const float* To = Tg + ((size_t)(bh*16 + ch))*4096;
    const float* Bo = Bg + ((size_t)(bh*16 + ch))*4096;
    float qs0[4] = {0,0,0,0}, qs1[4] = {0,0,0,0};   // Q.S0, regs F->O (valid on ls==0)
    __syncthreads();   // prev chunk done; staging safe

    // ---- stage K, Q, T, B, cumsum
    #pragma unroll
    for (int i = 0; i < 4; ++i) {
      int f4 = tid + 512*i;
      int row = f4 >> 5, c = (f4 & 31) * 4;
      *(float4*)&sK[row][c] = *(const float4*)(kg + (size_t)(t0+row)*128 + c);
      *(float4*)&sQ[row][c] = *(const float4*)(qg + (size_t)(t0+row)*128 + c);
    }
    #pragma unroll
    for (int i = 0; i < 2; ++i) {
      int f4 = tid + 512*i;
      int row = f4 >> 4, c = (f4 & 15) * 4;
      *(float4*)&sT[row][c]  = *(const float4*)(To + row*64 + c);
      *(float4*)&sBB[row][c] = *(const float4*)(Bo + row*64 + c);
    }
    if (tid < 64) {
      float x = gg[t0 + tid];
      #pragma unroll
      for (int o = 1; o < 64; o <<= 1) {
        float y = __shfl_up(x, o);
        if (tid >= o) x += y;
      }
      lL[tid] = x;
      bL[tid] = beg[t0 + tid];
    }
    __syncthreads();

    // ---- F: kv = K.S0, qs = Q.S0; RHS -> sW, qs -> regs
    {
      const int r0 = rg*2, r1 = r0 + 1;
      float ak0[4] = {0,0,0,0}, ak1[4] = {0,0,0,0};
      float aq0[4] = {0,0,0,0}, aq1[4] = {0,0,0,0};
      if (ch) {
        #pragma unroll
        for (int st = 0; st < 8; ++st) {
          const int kk = st*16 + ls*4;     // interleaved k-split: bank-safe
          float4 s0 = *(const float4*)&sS0T[cg4+0][kk];
          float4 s1 = *(const float4*)&sS0T[cg4+1][kk];
          float4 s2 = *(const float4*)&sS0T[cg4+2][kk];
          float4 s3 = *(const float4*)&sS0T[cg4+3][kk];
          float4 kr0 = *(const float4*)&sK[r0][kk];
          float4 kr1 = *(const float4*)&sK[r1][kk];
          float4 qr0 = *(const float4*)&sQ[r0][kk];
          float4 qr1 = *(const float4*)&sQ[r1][kk];
          DOT4(ak0[0], kr0, s0); DOT4(ak0[1], kr0, s1); DOT4(ak0[2], kr0, s2); DOT4(ak0[3], kr0, s3);
          DOT4(ak1[0], kr1, s0); DOT4(ak1[1], kr1, s1); DOT4(ak1[2], kr1, s2); DOT4(ak1[3], kr1, s3);
          DOT4(aq0[0], qr0, s0); DOT4(aq0[1], qr0, s1); DOT4(aq0[2], qr0, s2); DOT4(aq0[3], qr0, s3);
          DOT4(aq1[0], qr1, s0); DOT4(aq1[1], qr1, s1); DOT4(aq1[2], qr1, s2); DOT4(aq1[3], qr1, s3);
        }
      }
      #pragma unroll
      for (int c = 0; c < 4; ++c) {
        RED2(ak0[c]); RED2(ak1[c]); RED2(aq0[c]); RED2(aq1[c]);
      }
      if (ls == 0) {
        float be0 = bL[r0], ga0 = __expf(lL[r0]);
        float be1 = bL[r1], ga1 = __expf(lL[r1]);
        float bg0 = be0*ga0, bg1 = be1*ga1;
        float4 v0 = *(const float4*)(vg + (size_t)(t0+r0)*128 + cg4);
        float4 v1 = *(const float4*)(vg + (size_t)(t0+r1)*128 + cg4);
        float4 w0, w1;
        w0.x = fmaf(-bg0, ak0[0], be0*v0.x);
        w0.y = fmaf(-bg0, ak0[1], be0*v0.y);
        w0.z = fmaf(-bg0, ak0[2], be0*v0.z);
        w0.w = fmaf(-bg0, ak0[3], be0*v0.w);
        w1.x = fmaf(-bg1, ak1[0], be1*v1.x);
        w1.y = fmaf(-bg1, ak1[1], be1*v1.y);
        w1.z = fmaf(-bg1, ak1[2], be1*v1.z);
        w1.w = fmaf(-bg1, ak1[3], be1*v1.w);
        *(float4*)&sW[r0][cg4] = w0;
        *(float4*)&sW[r1][cg4] = w1;
        #pragma unroll
        for (int c = 0; c < 4; ++c) { qs0[c] = aq0[c]; qs1[c] = aq1[c]; }
      }
    }
    __syncthreads();

    // ---- W = T * RHS; write sW2 (unscaled) + sW3T (scaled, transposed)
    {
      const int r0 = rg*2, r1 = r0 + 1;
      float4 a0 = {0,0,0,0}, a1 = {0,0,0,0};
      #pragma unroll
      for (int jst = 0; jst < 16; ++jst) {
        const int j = jst*4 + ls;
        float t0v = sT[r0][j], t1v = sT[r1][j];
        float4 r = *(const float4*)&sW[j][cg4];
        FMA4(a0, r, t0v);
        FMA4(a1, r, t1v);
      }
      RED2(a0.x); RED2(a0.y); RED2(a0.z); RED2(a0.w);
      RED2(a1.x); RED2(a1.y); RED2(a1.z); RED2(a1.w);
      if (ls == 0) {
        *(float4*)&sW2[r0][cg4] = a0;
        *(float4*)&sW2[r1][cg4] = a1;
        float sc0 = __expf(lL[63] - lL[r0]);
        float sc1 = __expf(lL[63] - lL[r1]);
        sW3T[cg4+0][r0] = a0.x*sc0; sW3T[cg4+1][r0] = a0.y*sc0;
        sW3T[cg4+2][r0] = a0.z*sc0; sW3T[cg4+3][r0] = a0.w*sc0;
        sW3T[cg4+0][r1] = a1.x*sc1; sW3T[cg4+1][r1] = a1.y*sc1;
        sW3T[cg4+2][r1] = a1.z*sc1; sW3T[cg4+3][r1] = a1.w*sc1;
      }
    }
    __syncthreads();

    // ---- O = gamma*qs + B.W2 -> global (no barrier needed before U)
    {
      const int r0 = rg*2, r1 = r0 + 1;
      float4 a0 = {0,0,0,0}, a1 = {0,0,0,0};
      #pragma unroll
      for (int jst = 0; jst < 16; ++jst) {
        const int j = jst*4 + ls;
        float b0v = sBB[r0][j], b1v = sBB[r1][j];
        float4 r = *(const float4*)&sW2[j][cg4];
        FMA4(a0, r, b0v);
        FMA4(a1, r, b1v);
      }
      RED2(a0.x); RED2(a0.y); RED2(a0.z); RED2(a0.w);
      RED2(a1.x); RED2(a1.y); RED2(a1.z); RED2(a1.w);
      if (ls == 0) {
        float ga0 = __expf(lL[r0]), ga1 = __expf(lL[r1]);
        float4 o0, o1;
        o0.x = fmaf(ga0, qs0[0], a0.x);
        o0.y = fmaf(ga0, qs0[1], a0.y);
        o0.z = fmaf(ga0, qs0[2], a0.z);
        o0.w = fmaf(ga0, qs0[3], a0.w);
        o1.x = fmaf(ga1, qs1[0], a1.x);
        o1.y = fmaf(ga1, qs1[1], a1.y);
        o1.z = fmaf(ga1, qs1[2], a1.z);
        o1.w = fmaf(ga1, qs1[3], a1.w);
        *(float4*)(og + (size_t)(t0+r0)*128 + cg4) = o0;
        *(float4*)(og + (size_t)(t0+r1)*128 + cg4) = o1;
      }
    }

    // ---- U: S0 = gC*S0 + K^T W3 (4 vcols x 4 k per thread, 4-way j-split)
    if (ch != 15) {
      const int kq = rg*4;
      float4 acc0 = {0,0,0,0}, acc1 = {0,0,0,0}, acc2 = {0,0,0,0}, acc3 = {0,0,0,0};
      #pragma unroll
      for (int jst = 0; jst < 4; ++jst) {
        const int jb = jst*16 + ls*4;
        float4 w0 = *(const float4*)&sW3T[cg4+0][jb];
        float4 w1 = *(const float4*)&sW3T[cg4+1][jb];
        float4 w2 = *(const float4*)&sW3T[cg4+2][jb];
        float4 w3 = *(const float4*)&sW3T[cg4+3][jb];
        float4 k0 = *(const float4*)&sK[jb+0][kq];
        float4 k1 = *(const float4*)&sK[jb+1][kq];
        float4 k2 = *(const float4*)&sK[jb+2][kq];
        float4 k3 = *(const float4*)&sK[jb+3][kq];
        FMA4(acc0, k0, w0.x); FMA4(acc0, k1, w0.y); FMA4(acc0, k2, w0.z); FMA4(acc0, k3, w0.w);
        FMA4(acc1, k0, w1.x); FMA4(acc1, k1, w1.y); FMA4(acc1, k2, w1.z); FMA4(acc1, k3, w1.w);
        FMA4(acc2, k0, w2.x); FMA4(acc2, k1, w2.y); FMA4(acc2, k2, w2.z); FMA4(acc2, k3, w2.w);
        FMA4(acc3, k0, w3.x); FMA4(acc3, k1, w3.y); FMA4(acc3, k2, w3.z); FMA4(acc3, k3, w3.w);
      }
      RED2(acc0.x); RED2(acc0.y); RED2(acc0.z); RED2(acc0.w);
      RED2(acc1.x); RED2(acc1.y); RED2(acc1.z); RED2(acc1.w);
      RED2(acc2.x); RED2(acc2.y); RED2(acc2.z); RED2(acc2.w);
      RED2(acc3.x); RED2(acc3.y); RED2(acc3.z); RED2(acc3.w);
      if (ls == 0) {
        float gC = __expf(lL[63]);
        float4 s;
        s = *(const float4*)&sS0T[cg4+0][kq];
        s.x = fmaf(gC,s.x,acc0.x); s.y = fmaf(gC,s.y,acc0.y); s.z = fmaf(gC,s.z,acc0.z); s.w = fmaf(gC,s.w,acc0.w);
        *(float4*)&sS0T[cg4+0][kq] = s;
        s = *(const float4*)&sS0T[cg4+1][kq];
        s.x = fmaf(gC,s.x,acc1.x); s.y = fmaf(gC,s.y,acc1.y); s.z = fmaf(gC,s.z,acc1.z); s.w = fmaf(gC,s.w,acc1.w);
        *(float4*)&sS0T[cg4+1][kq] = s;
        s = *(const float4*)&sS0T[cg4+2][kq];
        s.x = fmaf(gC,s.x,acc2.x); s.y = fmaf(gC,s.y,acc2.y); s.z = fmaf(gC,s.z,acc2.z); s.w = fmaf(gC,s.w,acc2.w);
        *(float4*)&sS0T[cg4+2][kq] = s;
        s = *(const float4*)&sS0T[cg4+3][kq];
        s.x = fmaf(gC,s.x,acc3.x); s.y = fmaf(gC,s.y,acc3.y); s.z = fmaf(gC,s.z,acc3.z); s.w = fmaf(gC,s.w,acc3.w);
        *(float4*)&sS0T[cg4+3][kq] = s;
      }
    }
  }
#undef DOT4
#undef FMA4
#undef RED2
}

// rmsnorm(o)*norm_w*silu(z) -> bf16 og; z bf16
__global__ __launch_bounds__(64) void gnorm_kernel(
    const float* __restrict__ ob, const unsigned short* __restrict__ zbb,
    const float* __restrict__ norm_w, unsigned short* __restrict__ og) {
  const int idx = blockIdx.x;
  const int t = idx & 1023;
  const int bh = idx >> 10;
  const int b = bh >> 3;
  const int h = bh & 7;
  const int tid = threadIdx.x;
  const float* o = ob + ((size_t)bh*T_ + t)*128;
  float2 ov = *(const float2*)(o + tid*2);
  float ss = fmaf(ov.x, ov.x, ov.y*ov.y);
  #pragma unroll
  for (int m=1; m<64; m<<=1) ss += __shfl_xor(ss, m);
  float inv = rsqrtf(ss*(1.f/128.f) + 1e-6f);
  size_t zoff = ((size_t)(b*T_+t))*1024 + (size_t)h*128 + tid*2;
  ushort2 zv = *(const ushort2*)(zbb + zoff);
  float z0 = bfu2f(zv.x), z1 = bfu2f(zv.y);
  float n0 = norm_w[tid*2], n1 = norm_w[tid*2+1];
  float r0 = ov.x*inv*n0 * z0/(1.f+expf(-z0));
  float r1 = ov.y*inv*n1 * z1/(1.f+expf(-z1));
  ushort2 ot;
  ot.x = f2bf(r0); ot.y = f2bf(r1);
  *(ushort2*)(og + zoff) = ot;
}

extern "C" void kernel_launch(void* const* d_in, const int* in_sizes, int n_in,
                              void* d_out, int out_size, void* d_ws, size_t ws_size,
                              hipStream_t stream) {
  const float* hs     = (const float*)d_in[0];
  const float* qkv_w  = (const float*)d_in[1];
  const float* z_w    = (const float*)d_in[2];
  const float* b_w    = (const float*)d_in[3];
  const float* a_w    = (const float*)d_in[4];
  const float* conv_w = (const float*)d_in[5];
  const float* dt_bias= (const float*)d_in[6];
  const float* A_log  = (const float*)d_in[7];
  const float* norm_w = (const float*)d_in[8];
  const float* out_w  = (const float*)d_in[9];
  float* out = (float*)d_out;

  char* wsp = (char*)d_ws;
  size_t off = 0;
  auto give = [&](size_t bytes)->char*{
    char* p = wsp + off; off += (bytes + 255) & ~(size_t)255; return p;
  };
  float* mixed  = (float*)give((size_t)MROWS*CONV_DIM_*4);  // 48 MB fp32 qkv
  unsigned short* zbuf = (unsigned short*)give((size_t)MROWS*1024*2);  // 8 MB
  unsigned short* outw_bf = (unsigned short*)give((size_t)HID_*1024*2); // 2 MB
  float* qb    = (float*)give((size_t)32*T_*128*4);          // 16 MB
  float* kb    = (float*)give((size_t)32*T_*128*4);          // 16 MB
  float* vb    = (float*)give((size_t)32*T_*128*4);          // 16 MB
  float* gbuf  = (float*)give((size_t)32*T_*4);
  float* beta  = (float*)give((size_t)32*T_*4);
  // overlays within mixed (48 MB = 12M floats), all stream-ordered:
  unsigned short* hs_hi = (unsigned short*)kb;
  unsigned short* hs_lo = (unsigned short*)kb + (size_t)MROWS*HID_;
  unsigned short* wc_hi = (unsigned short*)vb;
  unsigned short* wc_lo = (unsigned short*)vb + (size_t)CONV_DIM_*HID_;
  unsigned short* wz_bf = (unsigned short*)qb;
  float* ob = mixed;                                              // [0,4M) floats
  unsigned short* og = (unsigned short*)(mixed + (size_t)4*1024*1024); // [4M,6M)
  float* Tg = mixed + (size_t)6*1024*1024;                        // [6M,8M) = 8 MB
  float* Bg = mixed + (size_t)8*1024*1024;                        // [8M,10M) = 8 MB

  f2bf_split_kernel<<<dim3(MROWS*HID_/1024), 256, 0, stream>>>(hs, hs_hi, hs_lo, MROWS*HID_);
  f2bf_split_kernel<<<dim3(CONV_DIM_*HID_/1024), 256, 0, stream>>>(qkv_w, wc_hi, wc_lo, CONV_DIM_*HID_);
  f2bf_kernel<<<dim3(1024*HID_/1024), 256, 0, stream>>>(z_w, wz_bf, 1024*HID_);
  f2bf_kernel<<<dim3(1024*HID_/1024), 256, 0, stream>>>(out_w, outw_bf, 1024*HID_);

  gemm_mfma_split_kernel<<<dim3(CONV_DIM_/128, MROWS/128), 256, 0, stream>>>(
      hs_hi, hs_lo, wc_hi, wc_lo, mixed, MROWS, CONV_DIM_, HID_);
  gemm_mfma_kernel<1><<<dim3(1024/128, MROWS/128), 256, 0, stream>>>(
      hs_hi, wz_bf, zbuf, MROWS, 1024, HID_);
  proj_ba_kernel<<<dim3(MROWS), dim3(128), 0, stream>>>(hs, b_w, a_w, dt_bias, A_log, gbuf, beta);
  conv_route_kernel<<<dim3((B_*256*CONV_DIM_)/256), dim3(256), 0, stream>>>(mixed, conv_w, qb, kb, vb);
  scan_ab_kernel<<<dim3(512), dim3(256), 0, stream>>>(qb, kb, gbuf, beta, Tg, Bg);
  scan_seq_kernel<<<dim3(256), dim3(512), 0, stream>>>(qb, kb, vb, gbuf, beta, Tg, Bg, ob);
  gnorm_kernel<<<dim3(32*T_), dim3(64), 0, stream>>>(ob, zbuf, norm_w, og);
  gemm_mfma_kernel<0><<<dim3(1024/128, MROWS/128), 256, 0, stream>>>(og, outw_bf, out, MROWS, 1024, HID_);
}

// Round 2
// 457.726 us; speedup vs baseline: 1.2683x; 1.2683x over previous
//
#include <hip/hip_runtime.h>

#define B_ 4
#define T_ 1024
#define HID_ 1024
#define H_ 8
#define CONV_DIM_ 3072
#define MROWS (B_*T_)

typedef __bf16 bf16x8 __attribute__((ext_vector_type(8)));
typedef float f32x4 __attribute__((ext_vector_type(4)));

static __device__ __forceinline__ unsigned short f2bf(float f) {
  unsigned u = __float_as_uint(f);
  unsigned r = u + 0x7fffu + ((u >> 16) & 1u);   // RNE
  return (unsigned short)(r >> 16);
}
static __device__ __forceinline__ float bfu2f(unsigned short v) {
  return __uint_as_float(((unsigned)v) << 16);
}

// async global->LDS 16B. LDS dest must be wave-uniform base + lane*16 (m104/m108).
static __device__ __forceinline__ void gld16(void* lds, const void* g) {
  __builtin_amdgcn_global_load_lds(
      (const __attribute__((address_space(1))) unsigned int*)g,
      (__attribute__((address_space(3))) unsigned int*)lds, 16, 0, 0);
}

// fp32 -> bf16 elementwise
__global__ __launch_bounds__(256) void f2bf_kernel(
    const float* __restrict__ src, unsigned short* __restrict__ dst, int n) {
  int i = (blockIdx.x * 256 + threadIdx.x) * 4;
  if (i >= n) return;
  float4 v = *(const float4*)(src + i);
  ushort4 o;
  o.x = f2bf(v.x); o.y = f2bf(v.y); o.z = f2bf(v.z); o.w = f2bf(v.w);
  *(ushort4*)(dst + i) = o;
}

// fp32 -> (hi, lo) bf16 split
__global__ __launch_bounds__(256) void f2bf_split_kernel(
    const float* __restrict__ src, unsigned short* __restrict__ hi,
    unsigned short* __restrict__ lo, int n) {
  int i = (blockIdx.x * 256 + threadIdx.x) * 4;
  if (i >= n) return;
  float4 v = *(const float4*)(src + i);
  ushort4 h, l;
  h.x = f2bf(v.x); h.y = f2bf(v.y); h.z = f2bf(v.z); h.w = f2bf(v.w);
  l.x = f2bf(v.x - bfu2f(h.x));
  l.y = f2bf(v.y - bfu2f(h.y));
  l.z = f2bf(v.z - bfu2f(h.z));
  l.w = f2bf(v.w - bfu2f(h.w));
  *(ushort4*)(hi + i) = h;
  *(ushort4*)(lo + i) = l;
}

// Single-pass bf16 MFMA GEMM: C[M,N] = A[M,K] * W[N,K]^T. 128x128 tile, BK=32.
// Staging via global_load_lds (async direct-to-LDS).
template<int OUT_BF16>
__global__ __launch_bounds__(256) void gemm_mfma_kernel(
    const unsigned short* __restrict__ A, const unsigned short* __restrict__ W,
    void* __restrict__ Cv, int M, int N, int K) {
  __shared__ __align__(16) unsigned short lA[128*32];
  __shared__ __align__(16) unsigned short lB[128*32];
  const int tid  = threadIdx.x;
  const int lane = tid & 63;
  const int wv   = tid >> 6;
  const int wm   = (wv >> 1) * 64;
  const int wn   = (wv & 1) * 64;
  const int m16  = lane & 15;
  const int quad = lane >> 4;
  const int bm = blockIdx.y * 128;
  const int bn = blockIdx.x * 128;

  f32x4 acc[4][4];
  #pragma unroll
  for (int i = 0; i < 4; ++i)
    #pragma unroll
    for (int j = 0; j < 4; ++j)
      acc[i][j] = (f32x4){0.f, 0.f, 0.f, 0.f};

  const int r0 = tid >> 2, c0 = tid & 3;
  const int r1 = r0 + 64;
  const int g0 = (c0 ^ (r0 & 3)) * 8;
  const int g1 = (c0 ^ (r1 & 3)) * 8;
  const unsigned short* Ar0 = A + (size_t)(bm + r0) * K + g0;
  const unsigned short* Ar1 = A + (size_t)(bm + r1) * K + g1;
  const unsigned short* Wr0 = W + (size_t)(bn + r0) * K + g0;
  const unsigned short* Wr1 = W + (size_t)(bn + r1) * K + g1;
  unsigned short* sA0 = &lA[(size_t)tid * 8];        // byte off = wv*1024 + lane*16
  unsigned short* sA1 = &lA[(size_t)(tid + 256) * 8];
  unsigned short* sB0 = &lB[(size_t)tid * 8];
  unsigned short* sB1 = &lB[(size_t)(tid + 256) * 8];

  int offA[4], offB[4];
  #pragma unroll
  for (int i = 0; i < 4; ++i) {
    int ra = wm + i * 16 + m16;
    offA[i] = ra * 32 + (quad ^ (ra & 3)) * 8;
    int rb = wn + i * 16 + m16;
    offB[i] = rb * 32 + (quad ^ (rb & 3)) * 8;
  }

  for (int k0 = 0; k0 < K; k0 += 32) {
    gld16(sA0, Ar0 + k0);
    gld16(sA1, Ar1 + k0);
    gld16(sB0, Wr0 + k0);
    gld16(sB1, Wr1 + k0);
    __syncthreads();    // drains vmcnt (incl. global_load_lds)
    bf16x8 af[4], bfr[4];
    #pragma unroll
    for (int i = 0; i < 4; ++i) {
      af[i]  = *(const bf16x8*)&lA[offA[i]];
      bfr[i] = *(const bf16x8*)&lB[offB[i]];
    }
    #pragma unroll
    for (int mi = 0; mi < 4; ++mi)
      #pragma unroll
      for (int ni = 0; ni < 4; ++ni)
        acc[mi][ni] = __builtin_amdgcn_mfma_f32_16x16x32_bf16(af[mi], bfr[ni], acc[mi][ni], 0, 0, 0);
    __syncthreads();
  }

  #pragma unroll
  for (int mi = 0; mi < 4; ++mi) {
    #pragma unroll
    for (int r = 0; r < 4; ++r) {
      size_t row = (size_t)(bm + wm + mi * 16 + quad * 4 + r);
      #pragma unroll
      for (int ni = 0; ni < 4; ++ni) {
        int col = bn + wn + ni * 16 + m16;
        float val = acc[mi][ni][r];
        if (OUT_BF16) ((unsigned short*)Cv)[row * N + col] = f2bf(val);
        else          ((float*)Cv)[row * N + col] = val;
      }
    }
  }
}

// Split-precision MFMA GEMM: C ~= Ahi*Whi + Ahi*Wlo + Alo*Whi. fp32 out.
// Staging via global_load_lds.
__global__ __launch_bounds__(256) void gemm_mfma_split_kernel(
    const unsigned short* __restrict__ Ahi, const unsigned short* __restrict__ Alo,
    const unsigned short* __restrict__ Whi, const unsigned short* __restrict__ Wlo,
    float* __restrict__ C, int M, int N, int K) {
  __shared__ __align__(16) unsigned short lAh[128*32];
  __shared__ __align__(16) unsigned short lAl[128*32];
  __shared__ __align__(16) unsigned short lBh[128*32];
  __shared__ __align__(16) unsigned short lBl[128*32];
  const int tid  = threadIdx.x;
  const int lane = tid & 63;
  const int wv   = tid >> 6;
  const int wm   = (wv >> 1) * 64;
  const int wn   = (wv & 1) * 64;
  const int m16  = lane & 15;
  const int quad = lane >> 4;
  const int bm = blockIdx.y * 128;
  const int bn = blockIdx.x * 128;

  f32x4 acc[4][4];
  #pragma unroll
  for (int i = 0; i < 4; ++i)
    #pragma unroll
    for (int j = 0; j < 4; ++j)
      acc[i][j] = (f32x4){0.f, 0.f, 0.f, 0.f};

  const int r0 = tid >> 2, c0 = tid & 3;
  const int r1 = r0 + 64;
  const int g0 = (c0 ^ (r0 & 3)) * 8;
  const int g1 = (c0 ^ (r1 & 3)) * 8;
  const size_t oA0 = (size_t)(bm + r0) * K + g0;
  const size_t oA1 = (size_t)(bm + r1) * K + g1;
  const size_t oB0 = (size_t)(bn + r0) * K + g0;
  const size_t oB1 = (size_t)(bn + r1) * K + g1;
  const int s0 = tid * 8, s1 = (tid + 256) * 8;

  int offA[4], offB[4];
  #pragma unroll
  for (int i = 0; i < 4; ++i) {
    int ra = wm + i * 16 + m16;
    offA[i] = ra * 32 + (quad ^ (ra & 3)) * 8;
    int rb = wn + i * 16 + m16;
    offB[i] = rb * 32 + (quad ^ (rb & 3)) * 8;
  }

  for (int k0 = 0; k0 < K; k0 += 32) {
    gld16(&lAh[s0], Ahi + oA0 + k0);
    gld16(&lAh[s1], Ahi + oA1 + k0);
    gld16(&lAl[s0], Alo + oA0 + k0);
    gld16(&lAl[s1], Alo + oA1 + k0);
    gld16(&lBh[s0], Whi + oB0 + k0);
    gld16(&lBh[s1], Whi + oB1 + k0);
    gld16(&lBl[s0], Wlo + oB0 + k0);
    gld16(&lBl[s1], Wlo + oB1 + k0);
    __syncthreads();
    bf16x8 afh[4], bfh[4];
    #pragma unroll
    for (int i = 0; i < 4; ++i) {
      afh[i] = *(const bf16x8*)&lAh[offA[i]];
      bfh[i] = *(const bf16x8*)&lBh[offB[i]];
    }
    #pragma unroll
    for (int mi = 0; mi < 4; ++mi)
      #pragma unroll
      for (int ni = 0; ni < 4; ++ni)
        acc[mi][ni] = __builtin_amdgcn_mfma_f32_16x16x32_bf16(afh[mi], bfh[ni], acc[mi][ni], 0, 0, 0);
    {
      bf16x8 bfl[4];
      #pragma unroll
      for (int i = 0; i < 4; ++i) bfl[i] = *(const bf16x8*)&lBl[offB[i]];
      #pragma unroll
      for (int mi = 0; mi < 4; ++mi)
        #pragma unroll
        for (int ni = 0; ni < 4; ++ni)
          acc[mi][ni] = __builtin_amdgcn_mfma_f32_16x16x32_bf16(afh[mi], bfl[ni], acc[mi][ni], 0, 0, 0);
    }
    {
      bf16x8 afl[4];
      #pragma unroll
      for (int i = 0; i < 4; ++i) afl[i] = *(const bf16x8*)&lAl[offA[i]];
      #pragma unroll
      for (int mi = 0; mi < 4; ++mi)
        #pragma unroll
        for (int ni = 0; ni < 4; ++ni)
          acc[mi][ni] = __builtin_amdgcn_mfma_f32_16x16x32_bf16(afl[mi], bfh[ni], acc[mi][ni], 0, 0, 0);
    }
    __syncthreads();
  }

  #pragma unroll
  for (int mi = 0; mi < 4; ++mi) {
    #pragma unroll
    for (int r = 0; r < 4; ++r) {
      size_t row = (size_t)(bm + wm + mi * 16 + quad * 4 + r);
      #pragma unroll
      for (int ni = 0; ni < 4; ++ni)
        C[row * N + bn + wn + ni * 16 + m16] = acc[mi][ni][r];
    }
  }
}

// bb/aa projections fused with beta / g=log(alpha). Reads fp32 hs (exact).
__global__ __launch_bounds__(128) void proj_ba_kernel(
    const float* __restrict__ hs, const float* __restrict__ b_w, const float* __restrict__ a_w,
    const float* __restrict__ dt_bias, const float* __restrict__ A_log,
    float* __restrict__ gout, float* __restrict__ beta) {
  const int bt = blockIdx.x;
  const int b = bt >> 10;
  const int t = bt & 1023;
  const int tid = threadIdx.x;
  const int grp = tid >> 3;
  const int l8 = tid & 7;
  const int h = grp & 7;
  const bool isA = grp >= 8;
  const float* w = (isA ? a_w : b_w) + (size_t)h * HID_;
  const float* x = hs + (size_t)bt * HID_;
  float s = 0.f;
  for (int e = l8*4; e < HID_; e += 32){
    float4 xv = *(const float4*)(x + e);
    float4 wv = *(const float4*)(w + e);
    s = fmaf(xv.x, wv.x, s);
    s = fmaf(xv.y, wv.y, s);
    s = fmaf(xv.z, wv.z, s);
    s = fmaf(xv.w, wv.w, s);
  }
  s += __shfl_xor(s,1); s += __shfl_xor(s,2); s += __shfl_xor(s,4);
  if (l8 == 0) {
    size_t o = ((size_t)(b*H_ + h))*T_ + t;
    if (!isA) {
      beta[o] = 1.f/(1.f+expf(-s));
    } else {
      float xx = s + dt_bias[h];
      float sp = fmaxf(xx,0.f) + log1pf(expf(-fabsf(xx)));   // softplus
      gout[o] = -expf(A_log[h]) * sp;                        // g = log(alpha)
    }
  }
}

// causal depthwise conv (K=4), 4 t-steps per thread (7 loads -> 4 outputs)
__global__ __launch_bounds__(256) void conv_route_kernel(
    const float* __restrict__ mixed, const float* __restrict__ conv_w,
    float* __restrict__ qb, float* __restrict__ kb, float* __restrict__ vb) {
  const int idx = blockIdx.x*256 + threadIdx.x;
  const int c = idx % CONV_DIM_;
  const int bt4 = idx / CONV_DIM_;
  const int b = bt4 >> 8;            // T/4 = 256 groups
  const int t0 = (bt4 & 255) * 4;
  float w0=conv_w[c*4],w1=conv_w[c*4+1],w2=conv_w[c*4+2],w3=conv_w[c*4+3];
  float x[7];
  #pragma unroll
  for (int j=0;j<7;++j){
    int tt = t0 - 3 + j;
    x[j] = (tt >= 0) ? mixed[((size_t)(b*T_+tt))*CONV_DIM_ + c] : 0.f;
  }
  const int part = c >> 10;
  const int cc = c & 1023;
  const int hh = cc >> 7;
  const int d = cc & 127;
  float* dst = part==0 ? qb : (part==1 ? kb : vb);
  size_t base = (((size_t)(b*H_+hh))*T_ + t0)*128 + d;
  #pragma unroll
  for (int i=0;i<4;++i){
    float s = fmaf(w0,x[i],fmaf(w1,x[i+1],fmaf(w2,x[i+2],w3*x[i+3])));
    dst[base + (size_t)i*128] = s;
  }
}

// Parallel precompute: 512 blocks = (bh, chunk).
// T = (I+A)^-1 (unit lower), B = incl-lower decayed QK^T.
__global__ __launch_bounds__(256) void scan_ab_kernel(
    const float* __restrict__ qb, const float* __restrict__ kb,
    const float* __restrict__ gbuf, const float* __restrict__ bbuf,
    float* __restrict__ Tg, float* __restrict__ Bg) {
  const int blk = blockIdx.x;
  const int bh = blk >> 4;
  const int ch = blk & 15;
  const int t0 = ch * 64;
  const int tid = threadIdx.x;
  __shared__ float sK[64][132];
  __shared__ float sAA[64][68];
  __shared__ float lL[64];
  __shared__ float bL[64];
  const float* kg = kb + (size_t)bh*T_*128;
  const float* qg = qb + (size_t)bh*T_*128;
  float* To = Tg + (size_t)blk*4096;
  float* Bo = Bg + (size_t)blk*4096;

  #pragma unroll
  for (int i = 0; i < 8; ++i) {
    int f4 = tid + 256*i;
    int row = f4 >> 5, c = f4 & 31;
    *(float4*)&sK[row][c*4] = *(const float4*)(kg + (size_t)(t0+row)*128 + c*4);
  }
  if (tid < 64) {
    float x = gbuf[(size_t)bh*T_ + t0 + tid];
    #pragma unroll
    for (int o = 1; o < 64; o <<= 1) {
      float y = __shfl_up(x, o);
      if (tid >= o) x += y;
    }
    lL[tid] = x;
    bL[tid] = bbuf[(size_t)bh*T_ + t0 + tid];
  }
  __syncthreads();

  const int it = tid >> 4, jt = tid & 15;
  {
    float acc[4][4] = {};
    if (jt <= it) {
      for (int kk = 0; kk < 128; kk += 4) {
        float4 ka[4], kc[4];
        #pragma unroll
        for (int r = 0; r < 4; ++r) {
          ka[r] = *(const float4*)&sK[it*4+r][kk];
          kc[r] = *(const float4*)&sK[jt*4+r][kk];
        }
        #pragma unroll
        for (int a = 0; a < 4; ++a)
          #pragma unroll
          for (int b = 0; b < 4; ++b) {
            acc[a][b] = fmaf(ka[a].x, kc[b].x, acc[a][b]);
            acc[a][b] = fmaf(ka[a].y, kc[b].y, acc[a][b]);
            acc[a][b] = fmaf(ka[a].z, kc[b].z, acc[a][b]);
            acc[a][b] = fmaf(ka[a].w, kc[b].w, acc[a][b]);
          }
      }
    }
    #pragma unroll
    for (int a = 0; a < 4; ++a) {
      int i = it*4 + a;
      float bi = bL[i], li = lL[i];
      #pragma unroll
      for (int b = 0; b < 4; ++b) {
        int j = jt*4 + b;
        sAA[i][j] = (j < i) ? bi * __expf(li - lL[j]) * acc[a][b] : 0.f;
      }
    }
  }
  {
    float acc[4][4] = {};
    if (jt <= it) {
      for (int kk = 0; kk < 128; kk += 4) {
        float4 qa[4], kc[4];
        #pragma unroll
        for (int r = 0; r < 4; ++r) {
          qa[r] = *(const float4*)(qg + (size_t)(t0+it*4+r)*128 + kk);
          kc[r] = *(const float4*)&sK[jt*4+r][kk];
        }
        #pragma unroll
        for (int a = 0; a < 4; ++a)
          #pragma unroll
          for (int b = 0; b < 4; ++b) {
            acc[a][b] = fmaf(qa[a].x, kc[b].x, acc[a][b]);
            acc[a][b] = fmaf(qa[a].y, kc[b].y, acc[a][b]);
            acc[a][b] = fmaf(qa[a].z, kc[b].z, acc[a][b]);
            acc[a][b] = fmaf(qa[a].w, kc[b].w, acc[a][b]);
          }
      }
    }
    #pragma unroll
    for (int a = 0; a < 4; ++a) {
      int i = it*4 + a;
      float li = lL[i];
      #pragma unroll
      for (int b = 0; b < 4; ++b) {
        int j = jt*4 + b;
        Bo[i*64 + j] = (j <= i) ? __expf(li - lL[j]) * acc[a][b] : 0.f;
      }
    }
  }
  __syncthreads();

  // invert (I+A): 4 waves x 16 cols, rows rr+4m per thread; wave-local chain
  {
    const int w = tid >> 6;
    const int ln = tid & 63;
    const int colc = w*16 + (ln & 15);
    const int rr = ln >> 4;
    float rh[16];
    #pragma unroll
    for (int m=0;m<16;++m) rh[m] = (rr + 4*m == colc) ? 1.f : 0.f;
    for (int j = 0; j < 63; ++j) {
      int src = ((j & 3) << 4) | (ln & 15);
      float wj = __shfl(rh[j >> 2], src);
      #pragma unroll
      for (int m=0;m<16;++m)
        rh[m] = fmaf(-sAA[rr + 4*m][j], wj, rh[m]);
    }
    #pragma unroll
    for (int m=0;m<16;++m)
      To[(rr + 4*m)*64 + colc] = rh[m];
  }
}

// Sequential chunked scan, 512 threads (8 waves), UT-transform form.
// 256 blocks = 32 bh x 8 dv-slices(16).
// Round-0 structure (all phase results in LDS, no cross-barrier registers).
// F and U retiled for fewer LDS reads; W/O phases identical to round 0.
__global__ __launch_bounds__(512) void scan_seq_kernel(
    const float* __restrict__ qb, const float* __restrict__ kb, const float* __restrict__ vb,
    const float* __restrict__ gbuf, const float* __restrict__ bbuf,
    const float* __restrict__ Tg, const float* __restrict__ Bg,
    float* __restrict__ ob) {
  const int bh = blockIdx.x >> 3;
  const int sl = blockIdx.x & 7;
  const int tid = threadIdx.x;

  __shared__ float sK[64][132];
  __shared__ float sQ[64][132];
  __shared__ float sT[64][68];
  __shared__ float sBB[64][68];
  __shared__ float sS0T[16][132];
  __shared__ float sW[64][20];    // RHS
  __shared__ float sW2[64][20];   // W = T*RHS
  __shared__ float sW3T[16][68];  // W scaled, transposed [col][row] for U phase
  __shared__ float sQS[64][20];   // Q.S0
  __shared__ float lL[64];
  __shared__ float bL[64];
  // total static LDS = 131072 B (round-0 known-good)

  const float* kg = kb + (size_t)bh*T_*128;
  const float* qg = qb + (size_t)bh*T_*128;
  const float* vg = vb + (size_t)bh*T_*128 + sl*16;
  const float* gg = gbuf + (size_t)bh*T_;
  const float* beg = bbuf + (size_t)bh*T_;
  float* og = ob + (size_t)bh*T_*128 + sl*16;

  // round-0 decode (W/O phases)
  const int ro  = tid >> 3;          // 0..63 row
  const int rem = tid & 7;
  const int kh  = rem >> 2;          // 0/1 half
  const int cg  = (rem & 3) * 4;     // col group (0,4,8,12)
  // 4-way-split decode (F/U phases)
  const int ls  = tid & 3;               // reduction split
  const int cg4 = ((tid >> 2) & 3) * 4;  // col group
  const int rg  = tid >> 4;              // 0..31

  for (int z = tid; z < 16*132; z += 512) ((float*)sS0T)[z] = 0.f;

#define DOT4(acc, a, b) acc = fmaf((a).x,(b).x,fmaf((a).y,(b).y,fmaf((a).z,(b).z,fmaf((a).w,(b).w,acc))))
#define FMA4(acc, v4, s) acc.x = fmaf((v4).x,(s),acc.x); acc.y = fmaf((v4).y,(s),acc.y); \
                         acc.z = fmaf((v4).z,(s),acc.z); acc.w = fmaf((v4).w,(s),acc.w);
#define RED2(x) x += __shfl_xor(x,1); x += __shfl_xor(x,2);

  for (int ch = 0; ch < 16; ++ch) {
    const int t0 = ch * 64;
    const float* To = Tg + ((size_t)(bh*16 + ch))*4096;
    const float* Bo = Bg + ((size_t)(bh*16 + ch))*4096;
    __syncthreads();   // prev chunk's S0-update done; staging safe

    // ---- stage K, Q, T, B, cumsum
    #pragma unroll
    for (int i = 0; i < 4; ++i) {
      int f4 = tid + 512*i;
      int row = f4 >> 5, c = (f4 & 31) * 4;
      *(float4*)&sK[row][c] = *(const float4*)(kg + (size_t)(t0+row)*128 + c);
      *(float4*)&sQ[row][c] = *(const float4*)(qg + (size_t)(t0+row)*128 + c);
    }
    #pragma unroll
    for (int i = 0; i < 2; ++i) {
      int f4 = tid + 512*i;
      int row = f4 >> 4, c = (f4 & 15) * 4;
      *(float4*)&sT[row][c]  = *(const float4*)(To + row*64 + c);
      *(float4*)&sBB[row][c] = *(const float4*)(Bo + row*64 + c);
    }
    if (tid < 64) {
      float x = gg[t0 + tid];
      #pragma unroll
      for (int o = 1; o < 64; o <<= 1) {
        float y = __shfl_up(x, o);
        if (tid >= o) x += y;
      }
      lL[tid] = x;
      bL[tid] = beg[t0 + tid];
    }
    __syncthreads();

    // ---- F: kv = K.S0, qs = Q.S0 (2 rows x 4 cols, 4-way interleaved k-split);
    //      RHS -> sW, qs -> sQS (all results end in LDS; no cross-barrier regs)
    {
      const int r0 = rg*2, r1 = r0 + 1;
      float ak0[4] = {0,0,0,0}, ak1[4] = {0,0,0,0};
      float aq0[4] = {0,0,0,0}, aq1[4] = {0,0,0,0};
      if (ch) {
        #pragma unroll
        for (int st = 0; st < 8; ++st) {
          const int kk = st*16 + ls*4;     // interleaved k-split: 2-way banks (free)
          float4 s0 = *(const float4*)&sS0T[cg4+0][kk];
          float4 s1 = *(const float4*)&sS0T[cg4+1][kk];
          float4 s2 = *(const float4*)&sS0T[cg4+2][kk];
          float4 s3 = *(const float4*)&sS0T[cg4+3][kk];
          float4 kr0 = *(const float4*)&sK[r0][kk];
          float4 kr1 = *(const float4*)&sK[r1][kk];
          float4 qr0 = *(const float4*)&sQ[r0][kk];
          float4 qr1 = *(const float4*)&sQ[r1][kk];
          DOT4(ak0[0], kr0, s0); DOT4(ak0[1], kr0, s1); DOT4(ak0[2], kr0, s2); DOT4(ak0[3], kr0, s3);
          DOT4(ak1[0], kr1, s0); DOT4(ak1[1], kr1, s1); DOT4(ak1[2], kr1, s2); DOT4(ak1[3], kr1, s3);
          DOT4(aq0[0], qr0, s0); DOT4(aq0[1], qr0, s1); DOT4(aq0[2], qr0, s2); DOT4(aq0[3], qr0, s3);
          DOT4(aq1[0], qr1, s0); DOT4(aq1[1], qr1, s1); DOT4(aq1[2], qr1, s2); DOT4(aq1[3], qr1, s3);
        }
        #pragma unroll
        for (int c = 0; c < 4; ++c) {
          RED2(ak0[c]); RED2(ak1[c]); RED2(aq0[c]); RED2(aq1[c]);
        }
      }
      if (ls == 0) {
        float be0 = bL[r0], ga0 = __expf(lL[r0]);
        float be1 = bL[r1], ga1 = __expf(lL[r1]);
        float bg0 = be0*ga0, bg1 = be1*ga1;
        float4 v0 = *(const float4*)(vg + (size_t)(t0+r0)*128 + cg4);
        float4 v1 = *(const float4*)(vg + (size_t)(t0+r1)*128 + cg4);
        float4 w0, w1;
        w0.x = fmaf(-bg0, ak0[0], be0*v0.x);
        w0.y = fmaf(-bg0, ak0[1], be0*v0.y);
        w0.z = fmaf(-bg0, ak0[2], be0*v0.z);
        w0.w = fmaf(-bg0, ak0[3], be0*v0.w);
        w1.x = fmaf(-bg1, ak1[0], be1*v1.x);
        w1.y = fmaf(-bg1, ak1[1], be1*v1.y);
        w1.z = fmaf(-bg1, ak1[2], be1*v1.z);
        w1.w = fmaf(-bg1, ak1[3], be1*v1.w);
        *(float4*)&sW[r0][cg4] = w0;
        *(float4*)&sW[r1][cg4] = w1;
        float4 qs0; qs0.x=aq0[0]; qs0.y=aq0[1]; qs0.z=aq0[2]; qs0.w=aq0[3];
        float4 qs1; qs1.x=aq1[0]; qs1.y=aq1[1]; qs1.z=aq1[2]; qs1.w=aq1[3];
        *(float4*)&sQS[r0][cg4] = qs0;
        *(float4*)&sQS[r1][cg4] = qs1;
      }
    }
    __syncthreads();

    // ---- W = T * RHS (round-0, unchanged); write sW2 + sW3T (scaled, transposed)
    {
      float w0=0,w1=0,w2=0,w3=0;
      const int jbeg = kh * 32;
      for (int j = jbeg; j < jbeg + 32; ++j) {
        float tv = sT[ro][j];
        float4 r = *(const float4*)&sW[j][cg];
        w0 = fmaf(tv, r.x, w0);
        w1 = fmaf(tv, r.y, w1);
        w2 = fmaf(tv, r.z, w2);
        w3 = fmaf(tv, r.w, w3);
      }
      w0 += __shfl_xor(w0,4); w1 += __shfl_xor(w1,4);
      w2 += __shfl_xor(w2,4); w3 += __shfl_xor(w3,4);
      if (kh == 0) {
        float4 w; w.x=w0; w.y=w1; w.z=w2; w.w=w3;
        *(float4*)&sW2[ro][cg] = w;
        float sc = __expf(lL[63] - lL[ro]);
        sW3T[cg+0][ro] = w0*sc;
        sW3T[cg+1][ro] = w1*sc;
        sW3T[cg+2][ro] = w2*sc;
        sW3T[cg+3][ro] = w3*sc;
      }
    }
    __syncthreads();

    // ---- O = gamma*QS + B.W2 -> global (round-0, unchanged; no barrier before U)
    {
      float w0=0,w1=0,w2=0,w3=0;
      const int jbeg = kh * 32;
      for (int j = jbeg; j < jbeg + 32; ++j) {
        float bv = sBB[ro][j];
        float4 r = *(const float4*)&sW2[j][cg];
        w0 = fmaf(bv, r.x, w0);
        w1 = fmaf(bv, r.y, w1);
        w2 = fmaf(bv, r.z, w2);
        w3 = fmaf(bv, r.w, w3);
      }
      w0 += __shfl_xor(w0,4); w1 += __shfl_xor(w1,4);
      w2 += __shfl_xor(w2,4); w3 += __shfl_xor(w3,4);
      if (kh == 0) {
        float ga = __expf(lL[ro]);
        float4 qs = *(const float4*)&sQS[ro][cg];
        float4 o;
        o.x = fmaf(ga, qs.x, w0);
        o.y = fmaf(ga, qs.y, w1);
        o.z = fmaf(ga, qs.z, w2);
        o.w = fmaf(ga, qs.w, w3);
        *(float4*)(og + (size_t)(t0+ro)*128 + cg) = o;
      }
    }

    // ---- U: S0 = gC*S0 + K^T W3 (4 vcols x 4 k per thread, 4-way j-split)
    if (ch != 15) {
      const int kq = rg*4;
      float4 acc0 = {0,0,0,0}, acc1 = {0,0,0,0}, acc2 = {0,0,0,0}, acc3 = {0,0,0,0};
      #pragma unroll
      for (int jst = 0; jst < 4; ++jst) {
        const int jb = jst*16 + ls*4;
        float4 w0 = *(const float4*)&sW3T[cg4+0][jb];
        float4 w1 = *(const float4*)&sW3T[cg4+1][jb];
        float4 w2 = *(const float4*)&sW3T[cg4+2][jb];
        float4 w3 = *(const float4*)&sW3T[cg4+3][jb];
        float4 k0 = *(const float4*)&sK[jb+0][kq];
        float4 k1 = *(const float4*)&sK[jb+1][kq];
        float4 k2 = *(const float4*)&sK[jb+2][kq];
        float4 k3 = *(const float4*)&sK[jb+3][kq];
        FMA4(acc0, k0, w0.x); FMA4(acc0, k1, w0.y); FMA4(acc0, k2, w0.z); FMA4(acc0, k3, w0.w);
        FMA4(acc1, k0, w1.x); FMA4(acc1, k1, w1.y); FMA4(acc1, k2, w1.z); FMA4(acc1, k3, w1.w);
        FMA4(acc2, k0, w2.x); FMA4(acc2, k1, w2.y); FMA4(acc2, k2, w2.z); FMA4(acc2, k3, w2.w);
        FMA4(acc3, k0, w3.x); FMA4(acc3, k1, w3.y); FMA4(acc3, k2, w3.z); FMA4(acc3, k3, w3.w);
      }
      RED2(acc0.x); RED2(acc0.y); RED2(acc0.z); RED2(acc0.w);
      RED2(acc1.x); RED2(acc1.y); RED2(acc1.z); RED2(acc1.w);
      RED2(acc2.x); RED2(acc2.y); RED2(acc2.z); RED2(acc2.w);
      RED2(acc3.x); RED2(acc3.y); RED2(acc3.z); RED2(acc3.w);
      if (ls == 0) {
        float gC = __expf(lL[63]);
        float4 s;
        s = *(const float4*)&sS0T[cg4+0][kq];
        s.x = fmaf(gC,s.x,acc0.x); s.y = fmaf(gC,s.y,acc0.y); s.z = fmaf(gC,s.z,acc0.z); s.w = fmaf(gC,s.w,acc0.w);
        *(float4*)&sS0T[cg4+0][kq] = s;
        s = *(const float4*)&sS0T[cg4+1][kq];
        s.x = fmaf(gC,s.x,acc1.x); s.y = fmaf(gC,s.y,acc1.y); s.z = fmaf(gC,s.z,acc1.z); s.w = fmaf(gC,s.w,acc1.w);
        *(float4*)&sS0T[cg4+1][kq] = s;
        s = *(const float4*)&sS0T[cg4+2][kq];
        s.x = fmaf(gC,s.x,acc2.x); s.y = fmaf(gC,s.y,acc2.y); s.z = fmaf(gC,s.z,acc2.z); s.w = fmaf(gC,s.w,acc2.w);
        *(float4*)&sS0T[cg4+2][kq] = s;
        s = *(const float4*)&sS0T[cg4+3][kq];
        s.x = fmaf(gC,s.x,acc3.x); s.y = fmaf(gC,s.y,acc3.y); s.z = fmaf(gC,s.z,acc3.z); s.w = fmaf(gC,s.w,acc3.w);
        *(float4*)&sS0T[cg4+3][kq] = s;
      }
    }
  }
#undef DOT4
#undef FMA4
#undef RED2
}

// rmsnorm(o)*norm_w*silu(z) -> bf16 og; z bf16
__global__ __launch_bounds__(64) void gnorm_kernel(
    const float* __restrict__ ob, const unsigned short* __restrict__ zbb,
    const float* __restrict__ norm_w, unsigned short* __restrict__ og) {
  const int idx = blockIdx.x;
  const int t = idx & 1023;
  const int bh = idx >> 10;
  const int b = bh >> 3;
  const int h = bh & 7;
  const int tid = threadIdx.x;
  const float* o = ob + ((size_t)bh*T_ + t)*128;
  float2 ov = *(const float2*)(o + tid*2);
  float ss = fmaf(ov.x, ov.x, ov.y*ov.y);
  #pragma unroll
  for (int m=1; m<64; m<<=1) ss += __shfl_xor(ss, m);
  float inv = rsqrtf(ss*(1.f/128.f) + 1e-6f);
  size_t zoff = ((size_t)(b*T_+t))*1024 + (size_t)h*128 + tid*2;
  ushort2 zv = *(const ushort2*)(zbb + zoff);
  float z0 = bfu2f(zv.x), z1 = bfu2f(zv.y);
  float n0 = norm_w[tid*2], n1 = norm_w[tid*2+1];
  float r0 = ov.x*inv*n0 * z0/(1.f+expf(-z0));
  float r1 = ov.y*inv*n1 * z1/(1.f+expf(-z1));
  ushort2 ot;
  ot.x = f2bf(r0); ot.y = f2bf(r1);
  *(ushort2*)(og + zoff) = ot;
}

extern "C" void kernel_launch(void* const* d_in, const int* in_sizes, int n_in,
                              void* d_out, int out_size, void* d_ws, size_t ws_size,
                              hipStream_t stream) {
  const float* hs     = (const float*)d_in[0];
  const float* qkv_w  = (const float*)d_in[1];
  const float* z_w    = (const float*)d_in[2];
  const float* b_w    = (const float*)d_in[3];
  const float* a_w    = (const float*)d_in[4];
  const float* conv_w = (const float*)d_in[5];
  const float* dt_bias= (const float*)d_in[6];
  const float* A_log  = (const float*)d_in[7];
  const float* norm_w = (const float*)d_in[8];
  const float* out_w  = (const float*)d_in[9];
  float* out = (float*)d_out;

  char* wsp = (char*)d_ws;
  size_t off = 0;
  auto give = [&](size_t bytes)->char*{
    char* p = wsp + off; off += (bytes + 255) & ~(size_t)255; return p;
  };
  float* mixed  = (float*)give((size_t)MROWS*CONV_DIM_*4);  // 48 MB fp32 qkv
  unsigned short* zbuf = (unsigned short*)give((size_t)MROWS*1024*2);  // 8 MB
  unsigned short* outw_bf = (unsigned short*)give((size_t)HID_*1024*2); // 2 MB
  float* qb    = (float*)give((size_t)32*T_*128*4);          // 16 MB
  float* kb    = (float*)give((size_t)32*T_*128*4);          // 16 MB
  float* vb    = (float*)give((size_t)32*T_*128*4);          // 16 MB
  float* gbuf  = (float*)give((size_t)32*T_*4);
  float* beta  = (float*)give((size_t)32*T_*4);
  // overlays within mixed (48 MB = 12M floats), all stream-ordered:
  unsigned short* hs_hi = (unsigned short*)kb;
  unsigned short* hs_lo = (unsigned short*)kb + (size_t)MROWS*HID_;
  unsigned short* wc_hi = (unsigned short*)vb;
  unsigned short* wc_lo = (unsigned short*)vb + (size_t)CONV_DIM_*HID_;
  unsigned short* wz_bf = (unsigned short*)qb;
  float* ob = mixed;                                              // [0,4M) floats
  unsigned short* og = (unsigned short*)(mixed + (size_t)4*1024*1024); // [4M,6M)
  float* Tg = mixed + (size_t)6*1024*1024;                        // [6M,8M) = 8 MB
  float* Bg = mixed + (size_t)8*1024*1024;                        // [8M,10M) = 8 MB

  f2bf_split_kernel<<<dim3(MROWS*HID_/1024), 256, 0, stream>>>(hs, hs_hi, hs_lo, MROWS*HID_);
  f2bf_split_kernel<<<dim3(CONV_DIM_*HID_/1024), 256, 0, stream>>>(qkv_w, wc_hi, wc_lo, CONV_DIM_*HID_);
  f2bf_kernel<<<dim3(1024*HID_/1024), 256, 0, stream>>>(z_w, wz_bf, 1024*HID_);
  f2bf_kernel<<<dim3(1024*HID_/1024), 256, 0, stream>>>(out_w, outw_bf, 1024*HID_);

  gemm_mfma_split_kernel<<<dim3(CONV_DIM_/128, MROWS/128), 256, 0, stream>>>(
      hs_hi, hs_lo, wc_hi, wc_lo, mixed, MROWS, CONV_DIM_, HID_);
  gemm_mfma_kernel<1><<<dim3(1024/128, MROWS/128), 256, 0, stream>>>(
      hs_hi, wz_bf, zbuf, MROWS, 1024, HID_);
  proj_ba_kernel<<<dim3(MROWS), dim3(128), 0, stream>>>(hs, b_w, a_w, dt_bias, A_log, gbuf, beta);
  conv_route_kernel<<<dim3((B_*256*CONV_DIM_)/256), dim3(256), 0, stream>>>(mixed, conv_w, qb, kb, vb);
  scan_ab_kernel<<<dim3(512), dim3(256), 0, stream>>>(qb, kb, gbuf, beta, Tg, Bg);
  scan_seq_kernel<<<dim3(256), dim3(512), 0, stream>>>(qb, kb, vb, gbuf, beta, Tg, Bg, ob);
  gnorm_kernel<<<dim3(32*T_), dim3(64), 0, stream>>>(ob, zbuf, norm_w, og);
  gemm_mfma_kernel<0><<<dim3(1024/128, MROWS/128), 256, 0, stream>>>(og, outw_bf, out, MROWS, 1024, HID_);
}

// Round 3
// 421.555 us; speedup vs baseline: 1.3771x; 1.0858x over previous
//
#include <hip/hip_runtime.h>

#define B_ 4
#define T_ 1024
#define HID_ 1024
#define H_ 8
#define CONV_DIM_ 3072
#define MROWS (B_*T_)

typedef __bf16 bf16x8 __attribute__((ext_vector_type(8)));
typedef float f32x4 __attribute__((ext_vector_type(4)));

#define MFMA16(a,b,c) __builtin_amdgcn_mfma_f32_16x16x32_bf16((a),(b),(c),0,0,0)

static __device__ __forceinline__ unsigned short f2bf(float f) {
  unsigned u = __float_as_uint(f);
  unsigned r = u + 0x7fffu + ((u >> 16) & 1u);   // RNE
  return (unsigned short)(r >> 16);
}
static __device__ __forceinline__ float bfu2f(unsigned short v) {
  return __uint_as_float(((unsigned)v) << 16);
}
static __device__ __forceinline__ float4 recon4(ushort4 h, ushort4 l) {
  float4 r;
  r.x = bfu2f(h.x) + bfu2f(l.x);
  r.y = bfu2f(h.y) + bfu2f(l.y);
  r.z = bfu2f(h.z) + bfu2f(l.z);
  r.w = bfu2f(h.w) + bfu2f(l.w);
  return r;
}

// async global->LDS 16B. LDS dest must be wave-uniform base + lane*16 (m104/m108).
static __device__ __forceinline__ void gld16(void* lds, const void* g) {
  __builtin_amdgcn_global_load_lds(
      (const __attribute__((address_space(1))) unsigned int*)g,
      (__attribute__((address_space(3))) unsigned int*)lds, 16, 0, 0);
}

// fp32 -> bf16 elementwise
__global__ __launch_bounds__(256) void f2bf_kernel(
    const float* __restrict__ src, unsigned short* __restrict__ dst, int n) {
  int i = (blockIdx.x * 256 + threadIdx.x) * 4;
  if (i >= n) return;
  float4 v = *(const float4*)(src + i);
  ushort4 o;
  o.x = f2bf(v.x); o.y = f2bf(v.y); o.z = f2bf(v.z); o.w = f2bf(v.w);
  *(ushort4*)(dst + i) = o;
}

// fp32 -> (hi, lo) bf16 split
__global__ __launch_bounds__(256) void f2bf_split_kernel(
    const float* __restrict__ src, unsigned short* __restrict__ hi,
    unsigned short* __restrict__ lo, int n) {
  int i = (blockIdx.x * 256 + threadIdx.x) * 4;
  if (i >= n) return;
  float4 v = *(const float4*)(src + i);
  ushort4 h, l;
  h.x = f2bf(v.x); h.y = f2bf(v.y); h.z = f2bf(v.z); h.w = f2bf(v.w);
  l.x = f2bf(v.x - bfu2f(h.x));
  l.y = f2bf(v.y - bfu2f(h.y));
  l.z = f2bf(v.z - bfu2f(h.z));
  l.w = f2bf(v.w - bfu2f(h.w));
  *(ushort4*)(hi + i) = h;
  *(ushort4*)(lo + i) = l;
}

// Single-pass bf16 MFMA GEMM: C[M,N] = A[M,K] * W[N,K]^T. 128x128 tile, BK=32.
template<int OUT_BF16>
__global__ __launch_bounds__(256) void gemm_mfma_kernel(
    const unsigned short* __restrict__ A, const unsigned short* __restrict__ W,
    void* __restrict__ Cv, int M, int N, int K) {
  __shared__ __align__(16) unsigned short lA[128*32];
  __shared__ __align__(16) unsigned short lB[128*32];
  const int tid  = threadIdx.x;
  const int lane = tid & 63;
  const int wv   = tid >> 6;
  const int wm   = (wv >> 1) * 64;
  const int wn   = (wv & 1) * 64;
  const int m16  = lane & 15;
  const int quad = lane >> 4;
  const int bm = blockIdx.y * 128;
  const int bn = blockIdx.x * 128;

  f32x4 acc[4][4];
  #pragma unroll
  for (int i = 0; i < 4; ++i)
    #pragma unroll
    for (int j = 0; j < 4; ++j)
      acc[i][j] = (f32x4){0.f, 0.f, 0.f, 0.f};

  const int r0 = tid >> 2, c0 = tid & 3;
  const int r1 = r0 + 64;
  const int g0 = (c0 ^ (r0 & 3)) * 8;
  const int g1 = (c0 ^ (r1 & 3)) * 8;
  const unsigned short* Ar0 = A + (size_t)(bm + r0) * K + g0;
  const unsigned short* Ar1 = A + (size_t)(bm + r1) * K + g1;
  const unsigned short* Wr0 = W + (size_t)(bn + r0) * K + g0;
  const unsigned short* Wr1 = W + (size_t)(bn + r1) * K + g1;
  unsigned short* sA0 = &lA[(size_t)tid * 8];
  unsigned short* sA1 = &lA[(size_t)(tid + 256) * 8];
  unsigned short* sB0 = &lB[(size_t)tid * 8];
  unsigned short* sB1 = &lB[(size_t)(tid + 256) * 8];

  int offA[4], offB[4];
  #pragma unroll
  for (int i = 0; i < 4; ++i) {
    int ra = wm + i * 16 + m16;
    offA[i] = ra * 32 + (quad ^ (ra & 3)) * 8;
    int rb = wn + i * 16 + m16;
    offB[i] = rb * 32 + (quad ^ (rb & 3)) * 8;
  }

  for (int k0 = 0; k0 < K; k0 += 32) {
    gld16(sA0, Ar0 + k0);
    gld16(sA1, Ar1 + k0);
    gld16(sB0, Wr0 + k0);
    gld16(sB1, Wr1 + k0);
    __syncthreads();
    bf16x8 af[4], bfr[4];
    #pragma unroll
    for (int i = 0; i < 4; ++i) {
      af[i]  = *(const bf16x8*)&lA[offA[i]];
      bfr[i] = *(const bf16x8*)&lB[offB[i]];
    }
    #pragma unroll
    for (int mi = 0; mi < 4; ++mi)
      #pragma unroll
      for (int ni = 0; ni < 4; ++ni)
        acc[mi][ni] = MFMA16(af[mi], bfr[ni], acc[mi][ni]);
    __syncthreads();
  }

  #pragma unroll
  for (int mi = 0; mi < 4; ++mi) {
    #pragma unroll
    for (int r = 0; r < 4; ++r) {
      size_t row = (size_t)(bm + wm + mi * 16 + quad * 4 + r);
      #pragma unroll
      for (int ni = 0; ni < 4; ++ni) {
        int col = bn + wn + ni * 16 + m16;
        float val = acc[mi][ni][r];
        if (OUT_BF16) ((unsigned short*)Cv)[row * N + col] = f2bf(val);
        else          ((float*)Cv)[row * N + col] = val;
      }
    }
  }
}

// Split-precision MFMA GEMM: C ~= Ahi*Whi + Ahi*Wlo + Alo*Whi. fp32 out.
__global__ __launch_bounds__(256) void gemm_mfma_split_kernel(
    const unsigned short* __restrict__ Ahi, const unsigned short* __restrict__ Alo,
    const unsigned short* __restrict__ Whi, const unsigned short* __restrict__ Wlo,
    float* __restrict__ C, int M, int N, int K) {
  __shared__ __align__(16) unsigned short lAh[128*32];
  __shared__ __align__(16) unsigned short lAl[128*32];
  __shared__ __align__(16) unsigned short lBh[128*32];
  __shared__ __align__(16) unsigned short lBl[128*32];
  const int tid  = threadIdx.x;
  const int lane = tid & 63;
  const int wv   = tid >> 6;
  const int wm   = (wv >> 1) * 64;
  const int wn   = (wv & 1) * 64;
  const int m16  = lane & 15;
  const int quad = lane >> 4;
  const int bm = blockIdx.y * 128;
  const int bn = blockIdx.x * 128;

  f32x4 acc[4][4];
  #pragma unroll
  for (int i = 0; i < 4; ++i)
    #pragma unroll
    for (int j = 0; j < 4; ++j)
      acc[i][j] = (f32x4){0.f, 0.f, 0.f, 0.f};

  const int r0 = tid >> 2, c0 = tid & 3;
  const int r1 = r0 + 64;
  const int g0 = (c0 ^ (r0 & 3)) * 8;
  const int g1 = (c0 ^ (r1 & 3)) * 8;
  const size_t oA0 = (size_t)(bm + r0) * K + g0;
  const size_t oA1 = (size_t)(bm + r1) * K + g1;
  const size_t oB0 = (size_t)(bn + r0) * K + g0;
  const size_t oB1 = (size_t)(bn + r1) * K + g1;
  const int s0 = tid * 8, s1 = (tid + 256) * 8;

  int offA[4], offB[4];
  #pragma unroll
  for (int i = 0; i < 4; ++i) {
    int ra = wm + i * 16 + m16;
    offA[i] = ra * 32 + (quad ^ (ra & 3)) * 8;
    int rb = wn + i * 16 + m16;
    offB[i] = rb * 32 + (quad ^ (rb & 3)) * 8;
  }

  for (int k0 = 0; k0 < K; k0 += 32) {
    gld16(&lAh[s0], Ahi + oA0 + k0);
    gld16(&lAh[s1], Ahi + oA1 + k0);
    gld16(&lAl[s0], Alo + oA0 + k0);
    gld16(&lAl[s1], Alo + oA1 + k0);
    gld16(&lBh[s0], Whi + oB0 + k0);
    gld16(&lBh[s1], Whi + oB1 + k0);
    gld16(&lBl[s0], Wlo + oB0 + k0);
    gld16(&lBl[s1], Wlo + oB1 + k0);
    __syncthreads();
    bf16x8 afh[4], bfh[4];
    #pragma unroll
    for (int i = 0; i < 4; ++i) {
      afh[i] = *(const bf16x8*)&lAh[offA[i]];
      bfh[i] = *(const bf16x8*)&lBh[offB[i]];
    }
    #pragma unroll
    for (int mi = 0; mi < 4; ++mi)
      #pragma unroll
      for (int ni = 0; ni < 4; ++ni)
        acc[mi][ni] = MFMA16(afh[mi], bfh[ni], acc[mi][ni]);
    {
      bf16x8 bfl[4];
      #pragma unroll
      for (int i = 0; i < 4; ++i) bfl[i] = *(const bf16x8*)&lBl[offB[i]];
      #pragma unroll
      for (int mi = 0; mi < 4; ++mi)
        #pragma unroll
        for (int ni = 0; ni < 4; ++ni)
          acc[mi][ni] = MFMA16(afh[mi], bfl[ni], acc[mi][ni]);
    }
    {
      bf16x8 afl[4];
      #pragma unroll
      for (int i = 0; i < 4; ++i) afl[i] = *(const bf16x8*)&lAl[offA[i]];
      #pragma unroll
      for (int mi = 0; mi < 4; ++mi)
        #pragma unroll
        for (int ni = 0; ni < 4; ++ni)
          acc[mi][ni] = MFMA16(afl[mi], bfh[ni], acc[mi][ni]);
    }
    __syncthreads();
  }

  #pragma unroll
  for (int mi = 0; mi < 4; ++mi) {
    #pragma unroll
    for (int r = 0; r < 4; ++r) {
      size_t row = (size_t)(bm + wm + mi * 16 + quad * 4 + r);
      #pragma unroll
      for (int ni = 0; ni < 4; ++ni)
        C[row * N + bn + wn + ni * 16 + m16] = acc[mi][ni][r];
    }
  }
}

// bb/aa projections fused with beta / g=log(alpha). Reads fp32 hs (exact).
__global__ __launch_bounds__(128) void proj_ba_kernel(
    const float* __restrict__ hs, const float* __restrict__ b_w, const float* __restrict__ a_w,
    const float* __restrict__ dt_bias, const float* __restrict__ A_log,
    float* __restrict__ gout, float* __restrict__ beta) {
  const int bt = blockIdx.x;
  const int b = bt >> 10;
  const int t = bt & 1023;
  const int tid = threadIdx.x;
  const int grp = tid >> 3;
  const int l8 = tid & 7;
  const int h = grp & 7;
  const bool isA = grp >= 8;
  const float* w = (isA ? a_w : b_w) + (size_t)h * HID_;
  const float* x = hs + (size_t)bt * HID_;
  float s = 0.f;
  for (int e = l8*4; e < HID_; e += 32){
    float4 xv = *(const float4*)(x + e);
    float4 wv = *(const float4*)(w + e);
    s = fmaf(xv.x, wv.x, s);
    s = fmaf(xv.y, wv.y, s);
    s = fmaf(xv.z, wv.z, s);
    s = fmaf(xv.w, wv.w, s);
  }
  s += __shfl_xor(s,1); s += __shfl_xor(s,2); s += __shfl_xor(s,4);
  if (l8 == 0) {
    size_t o = ((size_t)(b*H_ + h))*T_ + t;
    if (!isA) {
      beta[o] = 1.f/(1.f+expf(-s));
    } else {
      float xx = s + dt_bias[h];
      float sp = fmaxf(xx,0.f) + log1pf(expf(-fabsf(xx)));   // softplus
      gout[o] = -expf(A_log[h]) * sp;                        // g = log(alpha)
    }
  }
}

// causal depthwise conv (K=4), 4 t-steps per thread.
// q,k outputs -> bf16 hi/lo, PRE-SWIZZLED for scan kernels' MFMA frag reads:
//   elem (t,d) stored at row*128 + ((d>>3)^(t&7))*8 + (d&7).  v stays fp32.
__global__ __launch_bounds__(256) void conv_route_kernel(
    const float* __restrict__ mixed, const float* __restrict__ conv_w,
    unsigned short* __restrict__ qhi, unsigned short* __restrict__ qlo,
    unsigned short* __restrict__ khi, unsigned short* __restrict__ klo,
    float* __restrict__ vb) {
  const int idx = blockIdx.x*256 + threadIdx.x;
  const int c = idx % CONV_DIM_;
  const int bt4 = idx / CONV_DIM_;
  const int b = bt4 >> 8;            // T/4 = 256 groups
  const int t0 = (bt4 & 255) * 4;
  float w0=conv_w[c*4],w1=conv_w[c*4+1],w2=conv_w[c*4+2],w3=conv_w[c*4+3];
  float x[7];
  #pragma unroll
  for (int j=0;j<7;++j){
    int tt = t0 - 3 + j;
    x[j] = (tt >= 0) ? mixed[((size_t)(b*T_+tt))*CONV_DIM_ + c] : 0.f;
  }
  const int part = c >> 10;
  const int cc = c & 1023;
  const int hh = cc >> 7;
  const int d = cc & 127;
  if (part == 2) {
    size_t base = (((size_t)(b*H_+hh))*T_ + t0)*128 + d;
    #pragma unroll
    for (int i=0;i<4;++i){
      float s = fmaf(w0,x[i],fmaf(w1,x[i+1],fmaf(w2,x[i+2],w3*x[i+3])));
      vb[base + (size_t)i*128] = s;
    }
  } else {
    unsigned short* dh = (part==0) ? qhi : khi;
    unsigned short* dl = (part==0) ? qlo : klo;
    size_t rowb = ((size_t)(b*H_+hh))*T_ + t0;
    #pragma unroll
    for (int i=0;i<4;++i){
      float s = fmaf(w0,x[i],fmaf(w1,x[i+1],fmaf(w2,x[i+2],w3*x[i+3])));
      int tl = (t0 + i) & 7;
      int sw = (((d>>3) ^ tl) << 3) + (d & 7);
      unsigned short hv = f2bf(s);
      dh[(rowb + i)*128 + sw] = hv;
      dl[(rowb + i)*128 + sw] = f2bf(s - bfu2f(hv));
    }
  }
}

// Parallel precompute: 512 blocks = (bh, chunk).
// T = (I+A)^-1 (unit lower), B = incl-lower decayed QK^T.
// K/Q inputs are pre-swizzled bf16 hi/lo; outputs T,B as pre-swizzled bf16 hi/lo.
__global__ __launch_bounds__(256) void scan_ab_kernel(
    const unsigned short* __restrict__ qhi_g, const unsigned short* __restrict__ qlo_g,
    const unsigned short* __restrict__ khi_g, const unsigned short* __restrict__ klo_g,
    const float* __restrict__ gbuf, const float* __restrict__ bbuf,
    unsigned short* __restrict__ Thi_g, unsigned short* __restrict__ Tlo_g,
    unsigned short* __restrict__ Bhi_g, unsigned short* __restrict__ Blo_g) {
  const int blk = blockIdx.x;
  const int bh = blk >> 4;
  const int ch = blk & 15;
  const int t0 = ch * 64;
  const int tid = threadIdx.x;
  __shared__ float sK[64][132];
  __shared__ float sAA[64][68];
  __shared__ float lL[64];
  __shared__ float bL[64];
  unsigned short* Tho = Thi_g + (size_t)blk*4096;
  unsigned short* Tlo = Tlo_g + (size_t)blk*4096;
  unsigned short* Bho = Bhi_g + (size_t)blk*4096;
  unsigned short* Blo = Blo_g + (size_t)blk*4096;

  #pragma unroll
  for (int i = 0; i < 8; ++i) {
    int f4 = tid + 256*i;
    int row = f4 >> 5, c4 = (f4 & 31) * 4;
    int gr = t0 + row;
    size_t base = ((size_t)bh*1024 + gr)*128;
    int sw = (((c4>>3) ^ (gr&7)) << 3) + (c4 & 7);
    ushort4 h = *(const ushort4*)&khi_g[base + sw];
    ushort4 l = *(const ushort4*)&klo_g[base + sw];
    *(float4*)&sK[row][c4] = recon4(h, l);
  }
  if (tid < 64) {
    float x = gbuf[(size_t)bh*T_ + t0 + tid];
    #pragma unroll
    for (int o = 1; o < 64; o <<= 1) {
      float y = __shfl_up(x, o);
      if (tid >= o) x += y;
    }
    lL[tid] = x;
    bL[tid] = bbuf[(size_t)bh*T_ + t0 + tid];
  }
  __syncthreads();

  const int it = tid >> 4, jt = tid & 15;
  {
    float acc[4][4] = {};
    if (jt <= it) {
      for (int kk = 0; kk < 128; kk += 4) {
        float4 ka[4], kc[4];
        #pragma unroll
        for (int r = 0; r < 4; ++r) {
          ka[r] = *(const float4*)&sK[it*4+r][kk];
          kc[r] = *(const float4*)&sK[jt*4+r][kk];
        }
        #pragma unroll
        for (int a = 0; a < 4; ++a)
          #pragma unroll
          for (int b = 0; b < 4; ++b) {
            acc[a][b] = fmaf(ka[a].x, kc[b].x, acc[a][b]);
            acc[a][b] = fmaf(ka[a].y, kc[b].y, acc[a][b]);
            acc[a][b] = fmaf(ka[a].z, kc[b].z, acc[a][b]);
            acc[a][b] = fmaf(ka[a].w, kc[b].w, acc[a][b]);
          }
      }
    }
    #pragma unroll
    for (int a = 0; a < 4; ++a) {
      int i = it*4 + a;
      float bi = bL[i], li = lL[i];
      #pragma unroll
      for (int b = 0; b < 4; ++b) {
        int j = jt*4 + b;
        sAA[i][j] = (j < i) ? bi * __expf(li - lL[j]) * acc[a][b] : 0.f;
      }
    }
  }
  {
    float acc[4][4] = {};
    if (jt <= it) {
      size_t qbase[4]; int qrx[4];
      #pragma unroll
      for (int r = 0; r < 4; ++r) {
        int gr = t0 + it*4 + r;
        qbase[r] = ((size_t)bh*1024 + gr)*128;
        qrx[r] = gr & 7;
      }
      for (int kk = 0; kk < 128; kk += 4) {
        float4 qa[4], kc[4];
        #pragma unroll
        for (int r = 0; r < 4; ++r) {
          int sw = (((kk>>3) ^ qrx[r]) << 3) + (kk & 7);
          ushort4 h = *(const ushort4*)&qhi_g[qbase[r] + sw];
          ushort4 l = *(const ushort4*)&qlo_g[qbase[r] + sw];
          qa[r] = recon4(h, l);
          kc[r] = *(const float4*)&sK[jt*4+r][kk];
        }
        #pragma unroll
        for (int a = 0; a < 4; ++a)
          #pragma unroll
          for (int b = 0; b < 4; ++b) {
            acc[a][b] = fmaf(qa[a].x, kc[b].x, acc[a][b]);
            acc[a][b] = fmaf(qa[a].y, kc[b].y, acc[a][b]);
            acc[a][b] = fmaf(qa[a].z, kc[b].z, acc[a][b]);
            acc[a][b] = fmaf(qa[a].w, kc[b].w, acc[a][b]);
          }
      }
    }
    #pragma unroll
    for (int a = 0; a < 4; ++a) {
      int i = it*4 + a;
      float li = lL[i];
      #pragma unroll
      for (int b = 0; b < 4; ++b) {
        int j = jt*4 + b;
        float x = (j <= i) ? __expf(li - lL[j]) * acc[a][b] : 0.f;
        unsigned short hv = f2bf(x);
        int sidx = i*64 + (((j>>3) ^ (i&7)) << 3) + (j&7);
        Bho[sidx] = hv;
        Blo[sidx] = f2bf(x - bfu2f(hv));
      }
    }
  }
  __syncthreads();

  // invert (I+A): 4 waves x 16 cols, rows rr+4m per thread; wave-local chain
  {
    const int w = tid >> 6;
    const int ln = tid & 63;
    const int colc = w*16 + (ln & 15);
    const int rr = ln >> 4;
    float rh[16];
    #pragma unroll
    for (int m=0;m<16;++m) rh[m] = (rr + 4*m == colc) ? 1.f : 0.f;
    for (int j = 0; j < 63; ++j) {
      int src = ((j & 3) << 4) | (ln & 15);
      float wj = __shfl(rh[j >> 2], src);
      #pragma unroll
      for (int m=0;m<16;++m)
        rh[m] = fmaf(-sAA[rr + 4*m][j], wj, rh[m]);
    }
    #pragma unroll
    for (int m=0;m<16;++m) {
      int i2 = rr + 4*m;
      float x = rh[m];
      unsigned short hv = f2bf(x);
      int sidx = i2*64 + (((colc>>3) ^ (i2&7)) << 3) + (colc&7);
      Tho[sidx] = hv;
      Tlo[sidx] = f2bf(x - bfu2f(hv));
    }
  }
}

// Sequential chunked scan, 512 threads (8 waves), UT-transform, MFMA phases.
// 256 blocks = 32 bh x 8 dv-slices(16).
// F (K.S0 / Q.S0), W (T.RHS), O (B.W2) on matrix cores with bf16 hi/lo split;
// U (state update K^T.W3) stays fp32 VALU on the fp32 S0 master.
// All bf16 LDS tiles use XOR-swizzled 16B units: elem (r,k) at
// r*LD + ((k>>3)^(r&7))*8 + (k&7) — staged linearly from pre-swizzled global.
__global__ __launch_bounds__(512) void scan_seq_kernel(
    const unsigned short* __restrict__ khi_g, const unsigned short* __restrict__ klo_g,
    const unsigned short* __restrict__ qhi_g, const unsigned short* __restrict__ qlo_g,
    const float* __restrict__ vb,
    const float* __restrict__ gbuf, const float* __restrict__ bbuf,
    const unsigned short* __restrict__ Thi_g, const unsigned short* __restrict__ Tlo_g,
    const unsigned short* __restrict__ Bhi_g, const unsigned short* __restrict__ Blo_g,
    float* __restrict__ ob) {
  const int bh = blockIdx.x >> 3;
  const int sl = blockIdx.x & 7;
  const int tid = threadIdx.x;
  const int wv = tid >> 6;
  const int lane = tid & 63;
  const int v16 = lane & 15;
  const int quad = lane >> 4;
  const int tb = (wv & 3) * 16;
  const bool isQ = (wv >= 4);

  __shared__ __align__(16) unsigned short KhiL[64*128];
  __shared__ __align__(16) unsigned short KloL[64*128];
  __shared__ __align__(16) unsigned short QhiL[64*128];
  __shared__ __align__(16) unsigned short QloL[64*128];
  __shared__ __align__(16) unsigned short ThiL[64*64];
  __shared__ __align__(16) unsigned short TloL[64*64];
  __shared__ __align__(16) unsigned short BhiL[64*64];
  __shared__ __align__(16) unsigned short BloL[64*64];
  __shared__ float sS0T[16][132];                     // fp32 state master [v][k]
  __shared__ __align__(16) unsigned short S0h[16*128];  // bf16 hi/lo copies (swizzled)
  __shared__ __align__(16) unsigned short S0l[16*128];
  __shared__ __align__(16) unsigned short WTh[16*64];   // RHS^T hi/lo (swizzled)
  __shared__ __align__(16) unsigned short WTl[16*64];
  __shared__ __align__(16) unsigned short W2Th[16*64];  // W2^T hi/lo
  __shared__ __align__(16) unsigned short W2Tl[16*64];
  __shared__ float sW3T[16][68];                     // W3^T fp32 for U
  __shared__ float lL[64];
  __shared__ float bL[64];
  // total static LDS = 128000 B

  const unsigned short* kh  = khi_g + (size_t)bh*131072;
  const unsigned short* klp = klo_g + (size_t)bh*131072;
  const unsigned short* qh  = qhi_g + (size_t)bh*131072;
  const unsigned short* qlp = qlo_g + (size_t)bh*131072;
  const float* vg = vb + (size_t)bh*T_*128 + sl*16;
  const float* gg = gbuf + (size_t)bh*T_;
  const float* beg = bbuf + (size_t)bh*T_;
  float* og = ob + (size_t)bh*T_*128 + sl*16;

  // U decode
  const int ls = tid & 3;
  const int cg4 = ((tid >> 2) & 3) * 4;
  const int kq = (tid >> 4) * 4;

  for (int z = tid; z < 16*132; z += 512) ((float*)sS0T)[z] = 0.f;

#define FMA4(acc, v4, s) acc.x = fmaf((v4).x,(s),acc.x); acc.y = fmaf((v4).y,(s),acc.y); \
                         acc.z = fmaf((v4).z,(s),acc.z); acc.w = fmaf((v4).w,(s),acc.w);
#define RED2(x) x += __shfl_xor(x,1); x += __shfl_xor(x,2);

  for (int ch = 0; ch < 16; ++ch) {
    const int t0 = ch * 64;
    __syncthreads();   // prev chunk's U/O done; staging safe

    // ---- stage (global_load_lds, linear copies of pre-swizzled buffers)
    {
      const size_t co = (size_t)t0 * 128;
      gld16(&KhiL[tid*8],        kh  + co + tid*8);
      gld16(&KhiL[4096 + tid*8], kh  + co + 4096 + tid*8);
      gld16(&KloL[tid*8],        klp + co + tid*8);
      gld16(&KloL[4096 + tid*8], klp + co + 4096 + tid*8);
      gld16(&QhiL[tid*8],        qh  + co + tid*8);
      gld16(&QhiL[4096 + tid*8], qh  + co + 4096 + tid*8);
      gld16(&QloL[tid*8],        qlp + co + tid*8);
      gld16(&QloL[4096 + tid*8], qlp + co + 4096 + tid*8);
      const size_t tbo = ((size_t)(bh*16 + ch)) * 4096;
      gld16(&ThiL[tid*8], Thi_g + tbo + tid*8);
      gld16(&TloL[tid*8], Tlo_g + tbo + tid*8);
      gld16(&BhiL[tid*8], Bhi_g + tbo + tid*8);
      gld16(&BloL[tid*8], Blo_g + tbo + tid*8);
      if (tid < 64) {
        float x = gg[t0 + tid];
        #pragma unroll
        for (int o = 1; o < 64; o <<= 1) {
          float y = __shfl_up(x, o);
          if (tid >= o) x += y;
        }
        lL[tid] = x;
        bL[tid] = beg[t0 + tid];
      }
    }
    __syncthreads();   // drains vmcnt (incl. global_load_lds)

    // ---- F: waves 0-3: kv = K.S0 tile; waves 4-7: qs = Q.S0 tile (MFMA)
    f32x4 facc = (f32x4){0.f,0.f,0.f,0.f};
    if (ch) {
      const unsigned short* Ah = isQ ? QhiL : KhiL;
      const unsigned short* Al = isQ ? QloL : KloL;
      const int ar = tb + v16;
      const int arx = ar & 7;
      const int brx = v16 & 7;
      #pragma unroll
      for (int ks = 0; ks < 4; ++ks) {
        const int u = 4*ks + quad;
        const int ao = ar*128 + ((u ^ arx) << 3);
        const int bo = v16*128 + ((u ^ brx) << 3);
        bf16x8 ahi = *(const bf16x8*)&Ah[ao];
        bf16x8 alo = *(const bf16x8*)&Al[ao];
        bf16x8 bhi = *(const bf16x8*)&S0h[bo];
        bf16x8 blo = *(const bf16x8*)&S0l[bo];
        facc = MFMA16(ahi, bhi, facc);
        facc = MFMA16(ahi, blo, facc);
        facc = MFMA16(alo, bhi, facc);
      }
    }
    float qsr0 = 0.f, qsr1 = 0.f, qsr2 = 0.f, qsr3 = 0.f;
    if (!isQ) {
      // RHS = beta*(V - gamma*kv); write transposed bf16 hi/lo
      const int t4 = tb + quad*4;
      float xr[4];
      #pragma unroll
      for (int r = 0; r < 4; ++r) {
        const int t = t4 + r;
        float be = bL[t], ga = __expf(lL[t]);
        float vvv = vg[(size_t)(t0 + t)*128 + v16];
        xr[r] = fmaf(-be*ga, facc[r], be*vvv);
      }
      ushort4 h4, l4;
      h4.x = f2bf(xr[0]); h4.y = f2bf(xr[1]); h4.z = f2bf(xr[2]); h4.w = f2bf(xr[3]);
      l4.x = f2bf(xr[0]-bfu2f(h4.x)); l4.y = f2bf(xr[1]-bfu2f(h4.y));
      l4.z = f2bf(xr[2]-bfu2f(h4.z)); l4.w = f2bf(xr[3]-bfu2f(h4.w));
      const int wo = v16*64 + (((t4>>3) ^ (v16&7)) << 3) + (t4 & 7);
      *(ushort4*)&WTh[wo] = h4;
      *(ushort4*)&WTl[wo] = l4;
    } else {
      qsr0 = facc[0]; qsr1 = facc[1]; qsr2 = facc[2]; qsr3 = facc[3];
    }
    __syncthreads();

    // ---- W = T * RHS (waves 0-3, MFMA); write W2^T hi/lo + W3^T fp32
    if (!isQ) {
      f32x4 acc = (f32x4){0.f,0.f,0.f,0.f};
      const int ar = tb + v16;
      const int arx = ar & 7;
      const int brx = v16 & 7;
      #pragma unroll
      for (int ks = 0; ks < 2; ++ks) {
        const int u = 4*ks + quad;
        const int ao = ar*64 + ((u ^ arx) << 3);
        const int bo = v16*64 + ((u ^ brx) << 3);
        bf16x8 thi = *(const bf16x8*)&ThiL[ao];
        bf16x8 tlo = *(const bf16x8*)&TloL[ao];
        bf16x8 rhi = *(const bf16x8*)&WTh[bo];
        bf16x8 rlo = *(const bf16x8*)&WTl[bo];
        acc = MFMA16(thi, rhi, acc);
        acc = MFMA16(thi, rlo, acc);
        acc = MFMA16(tlo, rhi, acc);
      }
      const int t4 = tb + quad*4;
      float Le = lL[63];
      float x0 = acc[0], x1 = acc[1], x2 = acc[2], x3 = acc[3];
      ushort4 h4, l4;
      h4.x = f2bf(x0); h4.y = f2bf(x1); h4.z = f2bf(x2); h4.w = f2bf(x3);
      l4.x = f2bf(x0-bfu2f(h4.x)); l4.y = f2bf(x1-bfu2f(h4.y));
      l4.z = f2bf(x2-bfu2f(h4.z)); l4.w = f2bf(x3-bfu2f(h4.w));
      const int wo = v16*64 + (((t4>>3) ^ (v16&7)) << 3) + (t4 & 7);
      *(ushort4*)&W2Th[wo] = h4;
      *(ushort4*)&W2Tl[wo] = l4;
      float4 w3v;
      w3v.x = x0 * __expf(Le - lL[t4+0]);
      w3v.y = x1 * __expf(Le - lL[t4+1]);
      w3v.z = x2 * __expf(Le - lL[t4+2]);
      w3v.w = x3 * __expf(Le - lL[t4+3]);
      *(float4*)&sW3T[v16][t4] = w3v;
    }
    __syncthreads();

    // ---- O = gamma*qs + B.W2 (waves 4-7, MFMA) -> global
    if (isQ) {
      f32x4 acc = (f32x4){0.f,0.f,0.f,0.f};
      const int ar = tb + v16;
      const int arx = ar & 7;
      const int brx = v16 & 7;
      #pragma unroll
      for (int ks = 0; ks < 2; ++ks) {
        const int u = 4*ks + quad;
        const int ao = ar*64 + ((u ^ arx) << 3);
        const int bo = v16*64 + ((u ^ brx) << 3);
        bf16x8 bhi = *(const bf16x8*)&BhiL[ao];
        bf16x8 blo = *(const bf16x8*)&BloL[ao];
        bf16x8 whi = *(const bf16x8*)&W2Th[bo];
        bf16x8 wlo = *(const bf16x8*)&W2Tl[bo];
        acc = MFMA16(bhi, whi, acc);
        acc = MFMA16(bhi, wlo, acc);
        acc = MFMA16(blo, whi, acc);
      }
      const int t4 = tb + quad*4;
      og[(size_t)(t0+t4+0)*128 + v16] = fmaf(__expf(lL[t4+0]), qsr0, acc[0]);
      og[(size_t)(t0+t4+1)*128 + v16] = fmaf(__expf(lL[t4+1]), qsr1, acc[1]);
      og[(size_t)(t0+t4+2)*128 + v16] = fmaf(__expf(lL[t4+2]), qsr2, acc[2]);
      og[(size_t)(t0+t4+3)*128 + v16] = fmaf(__expf(lL[t4+3]), qsr3, acc[3]);
    }

    // ---- U: S0 = gC*S0 + K^T W3 (all waves, fp32 VALU, 4-way j-split)
    if (ch != 15) {
      auto ldK = [&](int j) -> float4 {
        int o = j*128 + (((kq>>3) ^ (j&7)) << 3) + (kq & 7);
        return recon4(*(const ushort4*)&KhiL[o], *(const ushort4*)&KloL[o]);
      };
      float4 acc0 = {0,0,0,0}, acc1 = {0,0,0,0}, acc2 = {0,0,0,0}, acc3 = {0,0,0,0};
      #pragma unroll
      for (int jst = 0; jst < 4; ++jst) {
        const int jb = jst*16 + ls*4;
        float4 w0 = *(const float4*)&sW3T[cg4+0][jb];
        float4 w1 = *(const float4*)&sW3T[cg4+1][jb];
        float4 w2 = *(const float4*)&sW3T[cg4+2][jb];
        float4 w3 = *(const float4*)&sW3T[cg4+3][jb];
        float4 k0 = ldK(jb+0);
        float4 k1 = ldK(jb+1);
        float4 k2 = ldK(jb+2);
        float4 k3 = ldK(jb+3);
        FMA4(acc0, k0, w0.x); FMA4(acc0, k1, w0.y); FMA4(acc0, k2, w0.z); FMA4(acc0, k3, w0.w);
        FMA4(acc1, k0, w1.x); FMA4(acc1, k1, w1.y); FMA4(acc1, k2, w1.z); FMA4(acc1, k3, w1.w);
        FMA4(acc2, k0, w2.x); FMA4(acc2, k1, w2.y); FMA4(acc2, k2, w2.z); FMA4(acc2, k3, w2.w);
        FMA4(acc3, k0, w3.x); FMA4(acc3, k1, w3.y); FMA4(acc3, k2, w3.z); FMA4(acc3, k3, w3.w);
      }
      RED2(acc0.x); RED2(acc0.y); RED2(acc0.z); RED2(acc0.w);
      RED2(acc1.x); RED2(acc1.y); RED2(acc1.z); RED2(acc1.w);
      RED2(acc2.x); RED2(acc2.y); RED2(acc2.z); RED2(acc2.w);
      RED2(acc3.x); RED2(acc3.y); RED2(acc3.z); RED2(acc3.w);
      if (ls == 0) {
        float gC = __expf(lL[63]);
#define UWB(C, ACC) { \
        const int vvr = cg4 + C; \
        float4 s = *(const float4*)&sS0T[vvr][kq]; \
        s.x = fmaf(gC, s.x, ACC.x); s.y = fmaf(gC, s.y, ACC.y); \
        s.z = fmaf(gC, s.z, ACC.z); s.w = fmaf(gC, s.w, ACC.w); \
        *(float4*)&sS0T[vvr][kq] = s; \
        ushort4 h4, l4; \
        h4.x = f2bf(s.x); h4.y = f2bf(s.y); h4.z = f2bf(s.z); h4.w = f2bf(s.w); \
        l4.x = f2bf(s.x-bfu2f(h4.x)); l4.y = f2bf(s.y-bfu2f(h4.y)); \
        l4.z = f2bf(s.z-bfu2f(h4.z)); l4.w = f2bf(s.w-bfu2f(h4.w)); \
        const int so = vvr*128 + (((kq>>3) ^ (vvr&7)) << 3) + (kq & 7); \
        *(ushort4*)&S0h[so] = h4; \
        *(ushort4*)&S0l[so] = l4; }
        UWB(0, acc0)
        UWB(1, acc1)
        UWB(2, acc2)
        UWB(3, acc3)
#undef UWB
      }
    }
  }
#undef FMA4
#undef RED2
}

// rmsnorm(o)*norm_w*silu(z) -> bf16 og; z bf16
__global__ __launch_bounds__(64) void gnorm_kernel(
    const float* __restrict__ ob, const unsigned short* __restrict__ zbb,
    const float* __restrict__ norm_w, unsigned short* __restrict__ og) {
  const int idx = blockIdx.x;
  const int t = idx & 1023;
  const int bh = idx >> 10;
  const int b = bh >> 3;
  const int h = bh & 7;
  const int tid = threadIdx.x;
  const float* o = ob + ((size_t)bh*T_ + t)*128;
  float2 ov = *(const float2*)(o + tid*2);
  float ss = fmaf(ov.x, ov.x, ov.y*ov.y);
  #pragma unroll
  for (int m=1; m<64; m<<=1) ss += __shfl_xor(ss, m);
  float inv = rsqrtf(ss*(1.f/128.f) + 1e-6f);
  size_t zoff = ((size_t)(b*T_+t))*1024 + (size_t)h*128 + tid*2;
  ushort2 zv = *(const ushort2*)(zbb + zoff);
  float z0 = bfu2f(zv.x), z1 = bfu2f(zv.y);
  float n0 = norm_w[tid*2], n1 = norm_w[tid*2+1];
  float r0 = ov.x*inv*n0 * z0/(1.f+expf(-z0));
  float r1 = ov.y*inv*n1 * z1/(1.f+expf(-z1));
  ushort2 ot;
  ot.x = f2bf(r0); ot.y = f2bf(r1);
  *(ushort2*)(og + zoff) = ot;
}

extern "C" void kernel_launch(void* const* d_in, const int* in_sizes, int n_in,
                              void* d_out, int out_size, void* d_ws, size_t ws_size,
                              hipStream_t stream) {
  const float* hs     = (const float*)d_in[0];
  const float* qkv_w  = (const float*)d_in[1];
  const float* z_w    = (const float*)d_in[2];
  const float* b_w    = (const float*)d_in[3];
  const float* a_w    = (const float*)d_in[4];
  const float* conv_w = (const float*)d_in[5];
  const float* dt_bias= (const float*)d_in[6];
  const float* A_log  = (const float*)d_in[7];
  const float* norm_w = (const float*)d_in[8];
  const float* out_w  = (const float*)d_in[9];
  float* out = (float*)d_out;

  char* wsp = (char*)d_ws;
  size_t off = 0;
  auto give = [&](size_t bytes)->char*{
    char* p = wsp + off; off += (bytes + 255) & ~(size_t)255; return p;
  };
  float* mixed  = (float*)give((size_t)MROWS*CONV_DIM_*4);  // 48 MB fp32 qkv
  unsigned short* zbuf = (unsigned short*)give((size_t)MROWS*1024*2);  // 8 MB
  unsigned short* outw_bf = (unsigned short*)give((size_t)HID_*1024*2); // 2 MB
  float* qb    = (float*)give((size_t)32*T_*128*4);          // 16 MB
  float* kb    = (float*)give((size_t)32*T_*128*4);          // 16 MB
  float* vb    = (float*)give((size_t)32*T_*128*4);          // 16 MB
  float* gbuf  = (float*)give((size_t)32*T_*4);
  float* beta  = (float*)give((size_t)32*T_*4);
  // overlays, all stream-ordered:
  unsigned short* hs_hi = (unsigned short*)kb;
  unsigned short* hs_lo = (unsigned short*)kb + (size_t)MROWS*HID_;
  unsigned short* wc_hi = (unsigned short*)vb;
  unsigned short* wc_lo = (unsigned short*)vb + (size_t)CONV_DIM_*HID_;
  unsigned short* wz_bf = (unsigned short*)qb;
  // conv_route bf16 hi/lo q/k land back in qb/kb after the GEMMs consume hs/wz:
  unsigned short* qhi = (unsigned short*)qb;
  unsigned short* qlo = qhi + (size_t)32*T_*128;
  unsigned short* khi = (unsigned short*)kb;
  unsigned short* klo = khi + (size_t)32*T_*128;
  float* ob = mixed;                                              // [0,4M) floats
  unsigned short* og = (unsigned short*)(mixed + (size_t)4*1024*1024); // [4M,6M)
  // T/B bf16 hi/lo in mixed[6M..10.19M) floats (16.8 MB):
  unsigned short* Thi_g = (unsigned short*)(mixed + (size_t)6*1024*1024);
  unsigned short* Tlo_g = Thi_g + (size_t)512*4096;
  unsigned short* Bhi_g = Tlo_g + (size_t)512*4096;
  unsigned short* Blo_g = Bhi_g + (size_t)512*4096;

  f2bf_split_kernel<<<dim3(MROWS*HID_/1024), 256, 0, stream>>>(hs, hs_hi, hs_lo, MROWS*HID_);
  f2bf_split_kernel<<<dim3(CONV_DIM_*HID_/1024), 256, 0, stream>>>(qkv_w, wc_hi, wc_lo, CONV_DIM_*HID_);
  f2bf_kernel<<<dim3(1024*HID_/1024), 256, 0, stream>>>(z_w, wz_bf, 1024*HID_);
  f2bf_kernel<<<dim3(1024*HID_/1024), 256, 0, stream>>>(out_w, outw_bf, 1024*HID_);

  gemm_mfma_split_kernel<<<dim3(CONV_DIM_/128, MROWS/128), 256, 0, stream>>>(
      hs_hi, hs_lo, wc_hi, wc_lo, mixed, MROWS, CONV_DIM_, HID_);
  gemm_mfma_kernel<1><<<dim3(1024/128, MROWS/128), 256, 0, stream>>>(
      hs_hi, wz_bf, zbuf, MROWS, 1024, HID_);
  proj_ba_kernel<<<dim3(MROWS), dim3(128), 0, stream>>>(hs, b_w, a_w, dt_bias, A_log, gbuf, beta);
  conv_route_kernel<<<dim3((B_*256*CONV_DIM_)/256), dim3(256), 0, stream>>>(
      mixed, conv_w, qhi, qlo, khi, klo, vb);
  scan_ab_kernel<<<dim3(512), dim3(256), 0, stream>>>(
      qhi, qlo, khi, klo, gbuf, beta, Thi_g, Tlo_g, Bhi_g, Blo_g);
  scan_seq_kernel<<<dim3(256), dim3(512), 0, stream>>>(
      khi, klo, qhi, qlo, vb, gbuf, beta, Thi_g, Tlo_g, Bhi_g, Blo_g, ob);
  gnorm_kernel<<<dim3(32*T_), dim3(64), 0, stream>>>(ob, zbuf, norm_w, og);
  gemm_mfma_kernel<0><<<dim3(1024/128, MROWS/128), 256, 0, stream>>>(og, outw_bf, out, MROWS, 1024, HID_);
}

// Round 4
// 403.562 us; speedup vs baseline: 1.4385x; 1.0446x over previous
//
#include <hip/hip_runtime.h>

#define B_ 4
#define T_ 1024
#define HID_ 1024
#define H_ 8
#define CONV_DIM_ 3072
#define MROWS (B_*T_)

typedef __bf16 bf16x8 __attribute__((ext_vector_type(8)));
typedef float f32x4 __attribute__((ext_vector_type(4)));

#define MFMA16(a,b,c) __builtin_amdgcn_mfma_f32_16x16x32_bf16((a),(b),(c),0,0,0)

static __device__ __forceinline__ unsigned short f2bf(float f) {
  unsigned u = __float_as_uint(f);
  unsigned r = u + 0x7fffu + ((u >> 16) & 1u);   // RNE
  return (unsigned short)(r >> 16);
}
static __device__ __forceinline__ float bfu2f(unsigned short v) {
  return __uint_as_float(((unsigned)v) << 16);
}
static __device__ __forceinline__ float4 recon4(ushort4 h, ushort4 l) {
  float4 r;
  r.x = bfu2f(h.x) + bfu2f(l.x);
  r.y = bfu2f(h.y) + bfu2f(l.y);
  r.z = bfu2f(h.z) + bfu2f(l.z);
  r.w = bfu2f(h.w) + bfu2f(l.w);
  return r;
}

// async global->LDS 16B. LDS dest must be wave-uniform base + lane*16 (m104/m108).
static __device__ __forceinline__ void gld16(void* lds, const void* g) {
  __builtin_amdgcn_global_load_lds(
      (const __attribute__((address_space(1))) unsigned int*)g,
      (__attribute__((address_space(3))) unsigned int*)lds, 16, 0, 0);
}

// fp32 -> bf16 elementwise
__global__ __launch_bounds__(256) void f2bf_kernel(
    const float* __restrict__ src, unsigned short* __restrict__ dst, int n) {
  int i = (blockIdx.x * 256 + threadIdx.x) * 4;
  if (i >= n) return;
  float4 v = *(const float4*)(src + i);
  ushort4 o;
  o.x = f2bf(v.x); o.y = f2bf(v.y); o.z = f2bf(v.z); o.w = f2bf(v.w);
  *(ushort4*)(dst + i) = o;
}

// fp32 -> (hi, lo) bf16 split
__global__ __launch_bounds__(256) void f2bf_split_kernel(
    const float* __restrict__ src, unsigned short* __restrict__ hi,
    unsigned short* __restrict__ lo, int n) {
  int i = (blockIdx.x * 256 + threadIdx.x) * 4;
  if (i >= n) return;
  float4 v = *(const float4*)(src + i);
  ushort4 h, l;
  h.x = f2bf(v.x); h.y = f2bf(v.y); h.z = f2bf(v.z); h.w = f2bf(v.w);
  l.x = f2bf(v.x - bfu2f(h.x));
  l.y = f2bf(v.y - bfu2f(h.y));
  l.z = f2bf(v.z - bfu2f(h.z));
  l.w = f2bf(v.w - bfu2f(h.w));
  *(ushort4*)(hi + i) = h;
  *(ushort4*)(lo + i) = l;
}

// Single-pass bf16 MFMA GEMM: C[M,N] = A[M,K] * W[N,K]^T. 128x128 tile, BK=32.
template<int OUT_BF16>
__global__ __launch_bounds__(256) void gemm_mfma_kernel(
    const unsigned short* __restrict__ A, const unsigned short* __restrict__ W,
    void* __restrict__ Cv, int M, int N, int K) {
  __shared__ __align__(16) unsigned short lA[128*32];
  __shared__ __align__(16) unsigned short lB[128*32];
  const int tid  = threadIdx.x;
  const int lane = tid & 63;
  const int wv   = tid >> 6;
  const int wm   = (wv >> 1) * 64;
  const int wn   = (wv & 1) * 64;
  const int m16  = lane & 15;
  const int quad = lane >> 4;
  const int bm = blockIdx.y * 128;
  const int bn = blockIdx.x * 128;

  f32x4 acc[4][4];
  #pragma unroll
  for (int i = 0; i < 4; ++i)
    #pragma unroll
    for (int j = 0; j < 4; ++j)
      acc[i][j] = (f32x4){0.f, 0.f, 0.f, 0.f};

  const int r0 = tid >> 2, c0 = tid & 3;
  const int r1 = r0 + 64;
  const int g0 = (c0 ^ (r0 & 3)) * 8;
  const int g1 = (c0 ^ (r1 & 3)) * 8;
  const unsigned short* Ar0 = A + (size_t)(bm + r0) * K + g0;
  const unsigned short* Ar1 = A + (size_t)(bm + r1) * K + g1;
  const unsigned short* Wr0 = W + (size_t)(bn + r0) * K + g0;
  const unsigned short* Wr1 = W + (size_t)(bn + r1) * K + g1;
  unsigned short* sA0 = &lA[(size_t)tid * 8];
  unsigned short* sA1 = &lA[(size_t)(tid + 256) * 8];
  unsigned short* sB0 = &lB[(size_t)tid * 8];
  unsigned short* sB1 = &lB[(size_t)(tid + 256) * 8];

  int offA[4], offB[4];
  #pragma unroll
  for (int i = 0; i < 4; ++i) {
    int ra = wm + i * 16 + m16;
    offA[i] = ra * 32 + (quad ^ (ra & 3)) * 8;
    int rb = wn + i * 16 + m16;
    offB[i] = rb * 32 + (quad ^ (rb & 3)) * 8;
  }

  for (int k0 = 0; k0 < K; k0 += 32) {
    gld16(sA0, Ar0 + k0);
    gld16(sA1, Ar1 + k0);
    gld16(sB0, Wr0 + k0);
    gld16(sB1, Wr1 + k0);
    __syncthreads();
    bf16x8 af[4], bfr[4];
    #pragma unroll
    for (int i = 0; i < 4; ++i) {
      af[i]  = *(const bf16x8*)&lA[offA[i]];
      bfr[i] = *(const bf16x8*)&lB[offB[i]];
    }
    #pragma unroll
    for (int mi = 0; mi < 4; ++mi)
      #pragma unroll
      for (int ni = 0; ni < 4; ++ni)
        acc[mi][ni] = MFMA16(af[mi], bfr[ni], acc[mi][ni]);
    __syncthreads();
  }

  #pragma unroll
  for (int mi = 0; mi < 4; ++mi) {
    #pragma unroll
    for (int r = 0; r < 4; ++r) {
      size_t row = (size_t)(bm + wm + mi * 16 + quad * 4 + r);
      #pragma unroll
      for (int ni = 0; ni < 4; ++ni) {
        int col = bn + wn + ni * 16 + m16;
        float val = acc[mi][ni][r];
        if (OUT_BF16) ((unsigned short*)Cv)[row * N + col] = f2bf(val);
        else          ((float*)Cv)[row * N + col] = val;
      }
    }
  }
}

// Split-precision MFMA GEMM: C ~= Ahi*Whi + Ahi*Wlo + Alo*Whi. fp32 out.
__global__ __launch_bounds__(256) void gemm_mfma_split_kernel(
    const unsigned short* __restrict__ Ahi, const unsigned short* __restrict__ Alo,
    const unsigned short* __restrict__ Whi, const unsigned short* __restrict__ Wlo,
    float* __restrict__ C, int M, int N, int K) {
  __shared__ __align__(16) unsigned short lAh[128*32];
  __shared__ __align__(16) unsigned short lAl[128*32];
  __shared__ __align__(16) unsigned short lBh[128*32];
  __shared__ __align__(16) unsigned short lBl[128*32];
  const int tid  = threadIdx.x;
  const int lane = tid & 63;
  const int wv   = tid >> 6;
  const int wm   = (wv >> 1) * 64;
  const int wn   = (wv & 1) * 64;
  const int m16  = lane & 15;
  const int quad = lane >> 4;
  const int bm = blockIdx.y * 128;
  const int bn = blockIdx.x * 128;

  f32x4 acc[4][4];
  #pragma unroll
  for (int i = 0; i < 4; ++i)
    #pragma unroll
    for (int j = 0; j < 4; ++j)
      acc[i][j] = (f32x4){0.f, 0.f, 0.f, 0.f};

  const int r0 = tid >> 2, c0 = tid & 3;
  const int r1 = r0 + 64;
  const int g0 = (c0 ^ (r0 & 3)) * 8;
  const int g1 = (c0 ^ (r1 & 3)) * 8;
  const size_t oA0 = (size_t)(bm + r0) * K + g0;
  const size_t oA1 = (size_t)(bm + r1) * K + g1;
  const size_t oB0 = (size_t)(bn + r0) * K + g0;
  const size_t oB1 = (size_t)(bn + r1) * K + g1;
  const int s0 = tid * 8, s1 = (tid + 256) * 8;

  int offA[4], offB[4];
  #pragma unroll
  for (int i = 0; i < 4; ++i) {
    int ra = wm + i * 16 + m16;
    offA[i] = ra * 32 + (quad ^ (ra & 3)) * 8;
    int rb = wn + i * 16 + m16;
    offB[i] = rb * 32 + (quad ^ (rb & 3)) * 8;
  }

  for (int k0 = 0; k0 < K; k0 += 32) {
    gld16(&lAh[s0], Ahi + oA0 + k0);
    gld16(&lAh[s1], Ahi + oA1 + k0);
    gld16(&lAl[s0], Alo + oA0 + k0);
    gld16(&lAl[s1], Alo + oA1 + k0);
    gld16(&lBh[s0], Whi + oB0 + k0);
    gld16(&lBh[s1], Whi + oB1 + k0);
    gld16(&lBl[s0], Wlo + oB0 + k0);
    gld16(&lBl[s1], Wlo + oB1 + k0);
    __syncthreads();
    bf16x8 afh[4], bfh[4];
    #pragma unroll
    for (int i = 0; i < 4; ++i) {
      afh[i] = *(const bf16x8*)&lAh[offA[i]];
      bfh[i] = *(const bf16x8*)&lBh[offB[i]];
    }
    #pragma unroll
    for (int mi = 0; mi < 4; ++mi)
      #pragma unroll
      for (int ni = 0; ni < 4; ++ni)
        acc[mi][ni] = MFMA16(afh[mi], bfh[ni], acc[mi][ni]);
    {
      bf16x8 bfl[4];
      #pragma unroll
      for (int i = 0; i < 4; ++i) bfl[i] = *(const bf16x8*)&lBl[offB[i]];
      #pragma unroll
      for (int mi = 0; mi < 4; ++mi)
        #pragma unroll
        for (int ni = 0; ni < 4; ++ni)
          acc[mi][ni] = MFMA16(afh[mi], bfl[ni], acc[mi][ni]);
    }
    {
      bf16x8 afl[4];
      #pragma unroll
      for (int i = 0; i < 4; ++i) afl[i] = *(const bf16x8*)&lAl[offA[i]];
      #pragma unroll
      for (int mi = 0; mi < 4; ++mi)
        #pragma unroll
        for (int ni = 0; ni < 4; ++ni)
          acc[mi][ni] = MFMA16(afl[mi], bfh[ni], acc[mi][ni]);
    }
    __syncthreads();
  }

  #pragma unroll
  for (int mi = 0; mi < 4; ++mi) {
    #pragma unroll
    for (int r = 0; r < 4; ++r) {
      size_t row = (size_t)(bm + wm + mi * 16 + quad * 4 + r);
      #pragma unroll
      for (int ni = 0; ni < 4; ++ni)
        C[row * N + bn + wn + ni * 16 + m16] = acc[mi][ni][r];
    }
  }
}

// bb/aa projections fused with beta / g=log(alpha). Reads fp32 hs (exact).
__global__ __launch_bounds__(128) void proj_ba_kernel(
    const float* __restrict__ hs, const float* __restrict__ b_w, const float* __restrict__ a_w,
    const float* __restrict__ dt_bias, const float* __restrict__ A_log,
    float* __restrict__ gout, float* __restrict__ beta) {
  const int bt = blockIdx.x;
  const int b = bt >> 10;
  const int t = bt & 1023;
  const int tid = threadIdx.x;
  const int grp = tid >> 3;
  const int l8 = tid & 7;
  const int h = grp & 7;
  const bool isA = grp >= 8;
  const float* w = (isA ? a_w : b_w) + (size_t)h * HID_;
  const float* x = hs + (size_t)bt * HID_;
  float s = 0.f;
  for (int e = l8*4; e < HID_; e += 32){
    float4 xv = *(const float4*)(x + e);
    float4 wv = *(const float4*)(w + e);
    s = fmaf(xv.x, wv.x, s);
    s = fmaf(xv.y, wv.y, s);
    s = fmaf(xv.z, wv.z, s);
    s = fmaf(xv.w, wv.w, s);
  }
  s += __shfl_xor(s,1); s += __shfl_xor(s,2); s += __shfl_xor(s,4);
  if (l8 == 0) {
    size_t o = ((size_t)(b*H_ + h))*T_ + t;
    if (!isA) {
      beta[o] = 1.f/(1.f+expf(-s));
    } else {
      float xx = s + dt_bias[h];
      float sp = fmaxf(xx,0.f) + log1pf(expf(-fabsf(xx)));   // softplus
      gout[o] = -expf(A_log[h]) * sp;                        // g = log(alpha)
    }
  }
}

// causal depthwise conv (K=4), 4 t-steps per thread.
// q,k outputs -> bf16 hi/lo, PRE-SWIZZLED for scan kernels' MFMA frag reads:
//   elem (t,d) stored at row*128 + ((d>>3)^(t&7))*8 + (d&7).  v stays fp32.
__global__ __launch_bounds__(256) void conv_route_kernel(
    const float* __restrict__ mixed, const float* __restrict__ conv_w,
    unsigned short* __restrict__ qhi, unsigned short* __restrict__ qlo,
    unsigned short* __restrict__ khi, unsigned short* __restrict__ klo,
    float* __restrict__ vb) {
  const int idx = blockIdx.x*256 + threadIdx.x;
  const int c = idx % CONV_DIM_;
  const int bt4 = idx / CONV_DIM_;
  const int b = bt4 >> 8;            // T/4 = 256 groups
  const int t0 = (bt4 & 255) * 4;
  float w0=conv_w[c*4],w1=conv_w[c*4+1],w2=conv_w[c*4+2],w3=conv_w[c*4+3];
  float x[7];
  #pragma unroll
  for (int j=0;j<7;++j){
    int tt = t0 - 3 + j;
    x[j] = (tt >= 0) ? mixed[((size_t)(b*T_+tt))*CONV_DIM_ + c] : 0.f;
  }
  const int part = c >> 10;
  const int cc = c & 1023;
  const int hh = cc >> 7;
  const int d = cc & 127;
  if (part == 2) {
    size_t base = (((size_t)(b*H_+hh))*T_ + t0)*128 + d;
    #pragma unroll
    for (int i=0;i<4;++i){
      float s = fmaf(w0,x[i],fmaf(w1,x[i+1],fmaf(w2,x[i+2],w3*x[i+3])));
      vb[base + (size_t)i*128] = s;
    }
  } else {
    unsigned short* dh = (part==0) ? qhi : khi;
    unsigned short* dl = (part==0) ? qlo : klo;
    size_t rowb = ((size_t)(b*H_+hh))*T_ + t0;
    #pragma unroll
    for (int i=0;i<4;++i){
      float s = fmaf(w0,x[i],fmaf(w1,x[i+1],fmaf(w2,x[i+2],w3*x[i+3])));
      int tl = (t0 + i) & 7;
      int sw = (((d>>3) ^ tl) << 3) + (d & 7);
      unsigned short hv = f2bf(s);
      dh[(rowb + i)*128 + sw] = hv;
      dl[(rowb + i)*128 + sw] = f2bf(s - bfu2f(hv));
    }
  }
}

// Parallel precompute: 512 blocks = (bh, chunk).
// T = (I+A)^-1 (unit lower), B = incl-lower decayed QK^T.
// K/Q inputs are pre-swizzled bf16 hi/lo; outputs T,B as pre-swizzled bf16 hi/lo.
__global__ __launch_bounds__(256) void scan_ab_kernel(
    const unsigned short* __restrict__ qhi_g, const unsigned short* __restrict__ qlo_g,
    const unsigned short* __restrict__ khi_g, const unsigned short* __restrict__ klo_g,
    const float* __restrict__ gbuf, const float* __restrict__ bbuf,
    unsigned short* __restrict__ Thi_g, unsigned short* __restrict__ Tlo_g,
    unsigned short* __restrict__ Bhi_g, unsigned short* __restrict__ Blo_g) {
  const int blk = blockIdx.x;
  const int bh = blk >> 4;
  const int ch = blk & 15;
  const int t0 = ch * 64;
  const int tid = threadIdx.x;
  __shared__ float sK[64][132];
  __shared__ float sAA[64][68];
  __shared__ float lL[64];
  __shared__ float bL[64];
  unsigned short* Tho = Thi_g + (size_t)blk*4096;
  unsigned short* Tlo = Tlo_g + (size_t)blk*4096;
  unsigned short* Bho = Bhi_g + (size_t)blk*4096;
  unsigned short* Blo = Blo_g + (size_t)blk*4096;

  #pragma unroll
  for (int i = 0; i < 8; ++i) {
    int f4 = tid + 256*i;
    int row = f4 >> 5, c4 = (f4 & 31) * 4;
    int gr = t0 + row;
    size_t base = ((size_t)bh*1024 + gr)*128;
    int sw = (((c4>>3) ^ (gr&7)) << 3) + (c4 & 7);
    ushort4 h = *(const ushort4*)&khi_g[base + sw];
    ushort4 l = *(const ushort4*)&klo_g[base + sw];
    *(float4*)&sK[row][c4] = recon4(h, l);
  }
  if (tid < 64) {
    float x = gbuf[(size_t)bh*T_ + t0 + tid];
    #pragma unroll
    for (int o = 1; o < 64; o <<= 1) {
      float y = __shfl_up(x, o);
      if (tid >= o) x += y;
    }
    lL[tid] = x;
    bL[tid] = bbuf[(size_t)bh*T_ + t0 + tid];
  }
  __syncthreads();

  const int it = tid >> 4, jt = tid & 15;
  {
    float acc[4][4] = {};
    if (jt <= it) {
      for (int kk = 0; kk < 128; kk += 4) {
        float4 ka[4], kc[4];
        #pragma unroll
        for (int r = 0; r < 4; ++r) {
          ka[r] = *(const float4*)&sK[it*4+r][kk];
          kc[r] = *(const float4*)&sK[jt*4+r][kk];
        }
        #pragma unroll
        for (int a = 0; a < 4; ++a)
          #pragma unroll
          for (int b = 0; b < 4; ++b) {
            acc[a][b] = fmaf(ka[a].x, kc[b].x, acc[a][b]);
            acc[a][b] = fmaf(ka[a].y, kc[b].y, acc[a][b]);
            acc[a][b] = fmaf(ka[a].z, kc[b].z, acc[a][b]);
            acc[a][b] = fmaf(ka[a].w, kc[b].w, acc[a][b]);
          }
      }
    }
    #pragma unroll
    for (int a = 0; a < 4; ++a) {
      int i = it*4 + a;
      float bi = bL[i], li = lL[i];
      #pragma unroll
      for (int b = 0; b < 4; ++b) {
        int j = jt*4 + b;
        sAA[i][j] = (j < i) ? bi * __expf(li - lL[j]) * acc[a][b] : 0.f;
      }
    }
  }
  {
    float acc[4][4] = {};
    if (jt <= it) {
      size_t qbase[4]; int qrx[4];
      #pragma unroll
      for (int r = 0; r < 4; ++r) {
        int gr = t0 + it*4 + r;
        qbase[r] = ((size_t)bh*1024 + gr)*128;
        qrx[r] = gr & 7;
      }
      for (int kk = 0; kk < 128; kk += 4) {
        float4 qa[4], kc[4];
        #pragma unroll
        for (int r = 0; r < 4; ++r) {
          int sw = (((kk>>3) ^ qrx[r]) << 3) + (kk & 7);
          ushort4 h = *(const ushort4*)&qhi_g[qbase[r] + sw];
          ushort4 l = *(const ushort4*)&qlo_g[qbase[r] + sw];
          qa[r] = recon4(h, l);
          kc[r] = *(const float4*)&sK[jt*4+r][kk];
        }
        #pragma unroll
        for (int a = 0; a < 4; ++a)
          #pragma unroll
          for (int b = 0; b < 4; ++b) {
            acc[a][b] = fmaf(qa[a].x, kc[b].x, acc[a][b]);
            acc[a][b] = fmaf(qa[a].y, kc[b].y, acc[a][b]);
            acc[a][b] = fmaf(qa[a].z, kc[b].z, acc[a][b]);
            acc[a][b] = fmaf(qa[a].w, kc[b].w, acc[a][b]);
          }
      }
    }
    #pragma unroll
    for (int a = 0; a < 4; ++a) {
      int i = it*4 + a;
      float li = lL[i];
      #pragma unroll
      for (int b = 0; b < 4; ++b) {
        int j = jt*4 + b;
        float x = (j <= i) ? __expf(li - lL[j]) * acc[a][b] : 0.f;
        unsigned short hv = f2bf(x);
        int sidx = i*64 + (((j>>3) ^ (i&7)) << 3) + (j&7);
        Bho[sidx] = hv;
        Blo[sidx] = f2bf(x - bfu2f(hv));
      }
    }
  }
  __syncthreads();

  // invert (I+A): 4 waves x 16 cols, rows rr+4m per thread; wave-local chain
  {
    const int w = tid >> 6;
    const int ln = tid & 63;
    const int colc = w*16 + (ln & 15);
    const int rr = ln >> 4;
    float rh[16];
    #pragma unroll
    for (int m=0;m<16;++m) rh[m] = (rr + 4*m == colc) ? 1.f : 0.f;
    for (int j = 0; j < 63; ++j) {
      int src = ((j & 3) << 4) | (ln & 15);
      float wj = __shfl(rh[j >> 2], src);
      #pragma unroll
      for (int m=0;m<16;++m)
        rh[m] = fmaf(-sAA[rr + 4*m][j], wj, rh[m]);
    }
    #pragma unroll
    for (int m=0;m<16;++m) {
      int i2 = rr + 4*m;
      float x = rh[m];
      unsigned short hv = f2bf(x);
      int sidx = i2*64 + (((colc>>3) ^ (i2&7)) << 3) + (colc&7);
      Tho[sidx] = hv;
      Tlo[sidx] = f2bf(x - bfu2f(hv));
    }
  }
}

// Sequential chunked scan, 512 threads (8 waves), UT-transform, all-MFMA phases.
// 256 blocks = 32 bh x 8 dv-slices(16).
// F (K.S0 / Q.S0), W (T.RHS), O (B.W2), U (K^T.W3) all on matrix cores with
// bf16 hi/lo split. State S0 lives in per-wave f32 MFMA accumulators (sreg);
// only K is LDS-staged (double-buffered, prefetched one chunk ahead).
// Q/T/B fragments load directly global->registers (pre-swizzled layouts).
// Per-chunk cumsum of g is wave-local (every wave computes it; shfl access).
__global__ __launch_bounds__(512) void scan_seq_kernel(
    const unsigned short* __restrict__ khi_g, const unsigned short* __restrict__ klo_g,
    const unsigned short* __restrict__ qhi_g, const unsigned short* __restrict__ qlo_g,
    const float* __restrict__ vb,
    const float* __restrict__ gbuf, const float* __restrict__ bbuf,
    const unsigned short* __restrict__ Thi_g, const unsigned short* __restrict__ Tlo_g,
    const unsigned short* __restrict__ Bhi_g, const unsigned short* __restrict__ Blo_g,
    float* __restrict__ ob) {
  const int bh = blockIdx.x >> 3;
  const int sl = blockIdx.x & 7;
  const int tid = threadIdx.x;
  const int wv = tid >> 6;
  const int lane = tid & 63;
  const int v16 = lane & 15;
  const int quad = lane >> 4;
  const int tb = (wv & 3) * 16;     // t-block for F/W/O roles
  const bool isQ = (wv >= 4);
  const int vx = v16 & 7;

  __shared__ __align__(16) unsigned short KhiL[2][64*128];
  __shared__ __align__(16) unsigned short KloL[2][64*128];
  __shared__ __align__(16) unsigned short WTh[16*64],  WTl[16*64];   // RHS^T
  __shared__ __align__(16) unsigned short W2Th[16*64], W2Tl[16*64];  // W2^T
  __shared__ __align__(16) unsigned short W3Th[16*64], W3Tl[16*64];  // W3^T
  __shared__ __align__(16) unsigned short S0h[16*128], S0l[16*128];  // state bf16 copies
  // total static LDS = 86016 B

  const unsigned short* kh  = khi_g + (size_t)bh*131072;
  const unsigned short* klp = klo_g + (size_t)bh*131072;
  const unsigned short* qh  = qhi_g + (size_t)bh*131072;
  const unsigned short* qlp = qlo_g + (size_t)bh*131072;
  const float* vg = vb + (size_t)bh*T_*128 + sl*16;
  const float* gg = gbuf + (size_t)bh*T_;
  const float* beg = bbuf + (size_t)bh*T_;
  float* og = ob + (size_t)bh*T_*128 + sl*16;

  // Persistent state: this wave owns k-block [wv*16, wv*16+16) x 16 v.
  // Lane holds S0T'[k = wv*16 + quad*4 + r][v16] in sreg[r].
  f32x4 sreg = (f32x4){0.f, 0.f, 0.f, 0.f};
  const int kk0 = wv*16 + v16;        // A-frag row (k) for U
  const int k8 = kk0 >> 3, k7 = kk0 & 7;
  const int kq4 = (quad & 1) * 4;     // S0 write: low bits of k
  const int kr8 = (wv*16 + quad*4) >> 3;

  // prologue: stage K chunk 0 into buf 0
  gld16(&KhiL[0][tid*8],        kh + tid*8);
  gld16(&KhiL[0][4096 + tid*8], kh + 4096 + tid*8);
  gld16(&KloL[0][tid*8],        klp + tid*8);
  gld16(&KloL[0][4096 + tid*8], klp + 4096 + tid*8);

  for (int ch = 0; ch < 16; ++ch) {
    const int t0 = ch * 64;
    const int cur = ch & 1;
    __syncthreads();   // B0: K(ch) landed; S0h from U(ch-1) visible; W bufs reusable

    // prefetch K(ch+1) into other buffer (hidden under this chunk's compute)
    if (ch < 15) {
      const size_t co = (size_t)(t0 + 64) * 128;
      gld16(&KhiL[cur^1][tid*8],        kh + co + tid*8);
      gld16(&KhiL[cur^1][4096 + tid*8], kh + co + 4096 + tid*8);
      gld16(&KloL[cur^1][tid*8],        klp + co + tid*8);
      gld16(&KloL[cur^1][4096 + tid*8], klp + co + 4096 + tid*8);
    }

    // wave-local cumsum: lane t holds lL[t] (gv) and bL[t] (bv)
    float gv = gg[t0 + lane];
    #pragma unroll
    for (int o = 1; o < 64; o <<= 1) {
      float y = __shfl_up(gv, o);
      if (lane >= o) gv += y;
    }
    float bv = beg[t0 + lane];

    // per-role operand loads: global -> registers (pre-swizzled layouts)
    const int ar = tb + v16;
    const int arx = ar & 7;
    const size_t tbo = ((size_t)(bh*16 + ch)) * 4096;
    bf16x8 tfh0, tfh1, tfl0, tfl1;   // K-waves: T frags
    bf16x8 bfh0, bfh1, bfl0, bfl1;   // Q-waves: B frags
    bf16x8 qfh[4], qfl[4];           // Q-waves: Q frags
    if (!isQ) {
      int a0 = ar*64 + ((quad ^ arx) << 3);
      int a1 = ar*64 + (((4 + quad) ^ arx) << 3);
      tfh0 = *(const bf16x8*)&Thi_g[tbo + a0];
      tfh1 = *(const bf16x8*)&Thi_g[tbo + a1];
      tfl0 = *(const bf16x8*)&Tlo_g[tbo + a0];
      tfl1 = *(const bf16x8*)&Tlo_g[tbo + a1];
    } else {
      int a0 = ar*64 + ((quad ^ arx) << 3);
      int a1 = ar*64 + (((4 + quad) ^ arx) << 3);
      bfh0 = *(const bf16x8*)&Bhi_g[tbo + a0];
      bfh1 = *(const bf16x8*)&Bhi_g[tbo + a1];
      bfl0 = *(const bf16x8*)&Blo_g[tbo + a0];
      bfl1 = *(const bf16x8*)&Blo_g[tbo + a1];
      const size_t qco = (size_t)t0 * 128;
      #pragma unroll
      for (int ks = 0; ks < 4; ++ks) {
        int ao = ar*128 + (((4*ks + quad) ^ arx) << 3);
        qfh[ks] = *(const bf16x8*)&qh[qco + ao];
        qfl[ks] = *(const bf16x8*)&qlp[qco + ao];
      }
    }

    // ---- F: kv = K.S0 (waves 0-3) / qs = Q.S0 (waves 4-7); MFMA, 2 chains
    f32x4 facc = (f32x4){0.f,0.f,0.f,0.f};
    if (ch) {
      f32x4 f2 = (f32x4){0.f,0.f,0.f,0.f};
      #pragma unroll
      for (int ks = 0; ks < 4; ++ks) {
        const int u = 4*ks + quad;
        const int bo = v16*128 + ((u ^ vx) << 3);
        bf16x8 bhi = *(const bf16x8*)&S0h[bo];
        bf16x8 blo = *(const bf16x8*)&S0l[bo];
        bf16x8 ahi, alo;
        if (!isQ) {
          const int ao = ar*128 + ((u ^ arx) << 3);
          ahi = *(const bf16x8*)&KhiL[cur][ao];
          alo = *(const bf16x8*)&KloL[cur][ao];
        } else {
          ahi = qfh[ks]; alo = qfl[ks];
        }
        facc = MFMA16(ahi, bhi, facc);
        f2   = MFMA16(ahi, blo, f2);
        f2   = MFMA16(alo, bhi, f2);
      }
      facc[0] += f2[0]; facc[1] += f2[1]; facc[2] += f2[2]; facc[3] += f2[3];
    }
    const int t4 = tb + quad*4;
    const int wo = v16*64 + ((((t4>>3) ^ vx)) << 3) + (t4 & 7);
    f32x4 qacc = facc;          // Q-waves keep qs in regs until O
    if (!isQ) {
      // RHS = beta*(V - gamma*kv) -> WT hi/lo (transposed, swizzled)
      float xr[4];
      #pragma unroll
      for (int r = 0; r < 4; ++r) {
        const int t = t4 + r;
        float be = __shfl(bv, t);
        float ga = __expf(__shfl(gv, t));
        float vvv = vg[(size_t)(t0 + t)*128 + v16];
        xr[r] = fmaf(-be*ga, facc[r], be*vvv);
      }
      ushort4 h4, l4;
      h4.x = f2bf(xr[0]); h4.y = f2bf(xr[1]); h4.z = f2bf(xr[2]); h4.w = f2bf(xr[3]);
      l4.x = f2bf(xr[0]-bfu2f(h4.x)); l4.y = f2bf(xr[1]-bfu2f(h4.y));
      l4.z = f2bf(xr[2]-bfu2f(h4.z)); l4.w = f2bf(xr[3]-bfu2f(h4.w));
      *(ushort4*)&WTh[wo] = h4;
      *(ushort4*)&WTl[wo] = l4;
    }
    __syncthreads();   // B1: WT visible (also drains K prefetch; covered by F)

    // ---- W = T * RHS (waves 0-3, MFMA); write W2^T + W3^T (both bf16 hi/lo)
    if (!isQ) {
      f32x4 wa = (f32x4){0.f,0.f,0.f,0.f};
      f32x4 wb = (f32x4){0.f,0.f,0.f,0.f};
      {
        const int b0 = v16*64 + ((quad ^ vx) << 3);
        const int b1 = v16*64 + (((4 + quad) ^ vx) << 3);
        bf16x8 r0h = *(const bf16x8*)&WTh[b0];
        bf16x8 r0l = *(const bf16x8*)&WTl[b0];
        bf16x8 r1h = *(const bf16x8*)&WTh[b1];
        bf16x8 r1l = *(const bf16x8*)&WTl[b1];
        wa = MFMA16(tfh0, r0h, wa);
        wb = MFMA16(tfh0, r0l, wb);
        wb = MFMA16(tfl0, r0h, wb);
        wa = MFMA16(tfh1, r1h, wa);
        wb = MFMA16(tfh1, r1l, wb);
        wb = MFMA16(tfl1, r1h, wb);
      }
      float Le = __shfl(gv, 63);
      float x0 = wa[0]+wb[0], x1 = wa[1]+wb[1], x2 = wa[2]+wb[2], x3 = wa[3]+wb[3];
      ushort4 h4, l4;
      h4.x = f2bf(x0); h4.y = f2bf(x1); h4.z = f2bf(x2); h4.w = f2bf(x3);
      l4.x = f2bf(x0-bfu2f(h4.x)); l4.y = f2bf(x1-bfu2f(h4.y));
      l4.z = f2bf(x2-bfu2f(h4.z)); l4.w = f2bf(x3-bfu2f(h4.w));
      *(ushort4*)&W2Th[wo] = h4;
      *(ushort4*)&W2Tl[wo] = l4;
      float w30 = x0 * __expf(Le - __shfl(gv, t4+0));
      float w31 = x1 * __expf(Le - __shfl(gv, t4+1));
      float w32 = x2 * __expf(Le - __shfl(gv, t4+2));
      float w33 = x3 * __expf(Le - __shfl(gv, t4+3));
      ushort4 h3, l3;
      h3.x = f2bf(w30); h3.y = f2bf(w31); h3.z = f2bf(w32); h3.w = f2bf(w33);
      l3.x = f2bf(w30-bfu2f(h3.x)); l3.y = f2bf(w31-bfu2f(h3.y));
      l3.z = f2bf(w32-bfu2f(h3.z)); l3.w = f2bf(w33-bfu2f(h3.w));
      *(ushort4*)&W3Th[wo] = h3;
      *(ushort4*)&W3Tl[wo] = l3;
    }
    __syncthreads();   // B2: W2/W3 visible

    // ---- O = gamma*qs + B.W2 (waves 4-7, MFMA) -> global
    if (isQ) {
      f32x4 oa = (f32x4){0.f,0.f,0.f,0.f};
      f32x4 ob2 = (f32x4){0.f,0.f,0.f,0.f};
      const int b0 = v16*64 + ((quad ^ vx) << 3);
      const int b1 = v16*64 + (((4 + quad) ^ vx) << 3);
      bf16x8 w0h = *(const bf16x8*)&W2Th[b0];
      bf16x8 w0l = *(const bf16x8*)&W2Tl[b0];
      bf16x8 w1h = *(const bf16x8*)&W2Th[b1];
      bf16x8 w1l = *(const bf16x8*)&W2Tl[b1];
      oa  = MFMA16(bfh0, w0h, oa);
      ob2 = MFMA16(bfh0, w0l, ob2);
      ob2 = MFMA16(bfl0, w0h, ob2);
      oa  = MFMA16(bfh1, w1h, oa);
      ob2 = MFMA16(bfh1, w1l, ob2);
      ob2 = MFMA16(bfl1, w1h, ob2);
      #pragma unroll
      for (int r = 0; r < 4; ++r) {
        const int t = t4 + r;
        float ga = __expf(__shfl(gv, t));
        og[(size_t)(t0 + t)*128 + v16] = fmaf(ga, qacc[r], oa[r] + ob2[r]);
      }
    }

    // ---- U: sreg = gC*sreg + K^T.W3  (all waves, MFMA; A-frag built from
    //      scalar column reads of the staged K tile)
    if (ch != 15) {
      float gC = __expf(__shfl(gv, 63));
      sreg[0] *= gC; sreg[1] *= gC; sreg[2] *= gC; sreg[3] *= gC;
      f32x4 s2 = (f32x4){0.f,0.f,0.f,0.f};
      #pragma unroll
      for (int ks = 0; ks < 2; ++ks) {
        const int u = 4*ks + quad;
        const int tbase = u * 8;
        bf16x8 ahi, alo;
        #pragma unroll
        for (int j = 0; j < 8; ++j) {
          const int ad = (tbase + j)*128 + ((k8 ^ j) << 3) + k7;
          ahi[j] = *(const __bf16*)&KhiL[cur][ad];
          alo[j] = *(const __bf16*)&KloL[cur][ad];
        }
        const int bo = v16*64 + ((u ^ vx) << 3);
        bf16x8 bhi = *(const bf16x8*)&W3Th[bo];
        bf16x8 blo = *(const bf16x8*)&W3Tl[bo];
        sreg = MFMA16(ahi, bhi, sreg);
        s2   = MFMA16(ahi, blo, s2);
        s2   = MFMA16(alo, bhi, s2);
      }
      sreg[0] += s2[0]; sreg[1] += s2[1]; sreg[2] += s2[2]; sreg[3] += s2[3];
      // publish bf16 hi/lo state copies for next chunk's F
      const int so = v16*128 + ((kr8 ^ vx) << 3) + kq4;
      ushort4 h4, l4;
      h4.x = f2bf(sreg[0]); h4.y = f2bf(sreg[1]);
      h4.z = f2bf(sreg[2]); h4.w = f2bf(sreg[3]);
      l4.x = f2bf(sreg[0]-bfu2f(h4.x)); l4.y = f2bf(sreg[1]-bfu2f(h4.y));
      l4.z = f2bf(sreg[2]-bfu2f(h4.z)); l4.w = f2bf(sreg[3]-bfu2f(h4.w));
      *(ushort4*)&S0h[so] = h4;
      *(ushort4*)&S0l[so] = l4;
    }
  }
}

// rmsnorm(o)*norm_w*silu(z) -> bf16 og; z bf16
__global__ __launch_bounds__(64) void gnorm_kernel(
    const float* __restrict__ ob, const unsigned short* __restrict__ zbb,
    const float* __restrict__ norm_w, unsigned short* __restrict__ og) {
  const int idx = blockIdx.x;
  const int t = idx & 1023;
  const int bh = idx >> 10;
  const int b = bh >> 3;
  const int h = bh & 7;
  const int tid = threadIdx.x;
  const float* o = ob + ((size_t)bh*T_ + t)*128;
  float2 ov = *(const float2*)(o + tid*2);
  float ss = fmaf(ov.x, ov.x, ov.y*ov.y);
  #pragma unroll
  for (int m=1; m<64; m<<=1) ss += __shfl_xor(ss, m);
  float inv = rsqrtf(ss*(1.f/128.f) + 1e-6f);
  size_t zoff = ((size_t)(b*T_+t))*1024 + (size_t)h*128 + tid*2;
  ushort2 zv = *(const ushort2*)(zbb + zoff);
  float z0 = bfu2f(zv.x), z1 = bfu2f(zv.y);
  float n0 = norm_w[tid*2], n1 = norm_w[tid*2+1];
  float r0 = ov.x*inv*n0 * z0/(1.f+expf(-z0));
  float r1 = ov.y*inv*n1 * z1/(1.f+expf(-z1));
  ushort2 ot;
  ot.x = f2bf(r0); ot.y = f2bf(r1);
  *(ushort2*)(og + zoff) = ot;
}

extern "C" void kernel_launch(void* const* d_in, const int* in_sizes, int n_in,
                              void* d_out, int out_size, void* d_ws, size_t ws_size,
                              hipStream_t stream) {
  const float* hs     = (const float*)d_in[0];
  const float* qkv_w  = (const float*)d_in[1];
  const float* z_w    = (const float*)d_in[2];
  const float* b_w    = (const float*)d_in[3];
  const float* a_w    = (const float*)d_in[4];
  const float* conv_w = (const float*)d_in[5];
  const float* dt_bias= (const float*)d_in[6];
  const float* A_log  = (const float*)d_in[7];
  const float* norm_w = (const float*)d_in[8];
  const float* out_w  = (const float*)d_in[9];
  float* out = (float*)d_out;

  char* wsp = (char*)d_ws;
  size_t off = 0;
  auto give = [&](size_t bytes)->char*{
    char* p = wsp + off; off += (bytes + 255) & ~(size_t)255; return p;
  };
  float* mixed  = (float*)give((size_t)MROWS*CONV_DIM_*4);  // 48 MB fp32 qkv
  unsigned short* zbuf = (unsigned short*)give((size_t)MROWS*1024*2);  // 8 MB
  unsigned short* outw_bf = (unsigned short*)give((size_t)HID_*1024*2); // 2 MB
  float* qb    = (float*)give((size_t)32*T_*128*4);          // 16 MB
  float* kb    = (float*)give((size_t)32*T_*128*4);          // 16 MB
  float* vb    = (float*)give((size_t)32*T_*128*4);          // 16 MB
  float* gbuf  = (float*)give((size_t)32*T_*4);
  float* beta  = (float*)give((size_t)32*T_*4);
  // overlays, all stream-ordered:
  unsigned short* hs_hi = (unsigned short*)kb;
  unsigned short* hs_lo = (unsigned short*)kb + (size_t)MROWS*HID_;
  unsigned short* wc_hi = (unsigned short*)vb;
  unsigned short* wc_lo = (unsigned short*)vb + (size_t)CONV_DIM_*HID_;
  unsigned short* wz_bf = (unsigned short*)qb;
  // conv_route bf16 hi/lo q/k land back in qb/kb after the GEMMs consume hs/wz:
  unsigned short* qhi = (unsigned short*)qb;
  unsigned short* qlo = qhi + (size_t)32*T_*128;
  unsigned short* khi = (unsigned short*)kb;
  unsigned short* klo = khi + (size_t)32*T_*128;
  float* ob = mixed;                                              // [0,4M) floats
  unsigned short* og = (unsigned short*)(mixed + (size_t)4*1024*1024); // [4M,6M)
  // T/B bf16 hi/lo in mixed[6M..10.19M) floats (16.8 MB):
  unsigned short* Thi_g = (unsigned short*)(mixed + (size_t)6*1024*1024);
  unsigned short* Tlo_g = Thi_g + (size_t)512*4096;
  unsigned short* Bhi_g = Tlo_g + (size_t)512*4096;
  unsigned short* Blo_g = Bhi_g + (size_t)512*4096;

  f2bf_split_kernel<<<dim3(MROWS*HID_/1024), 256, 0, stream>>>(hs, hs_hi, hs_lo, MROWS*HID_);
  f2bf_split_kernel<<<dim3(CONV_DIM_*HID_/1024), 256, 0, stream>>>(qkv_w, wc_hi, wc_lo, CONV_DIM_*HID_);
  f2bf_kernel<<<dim3(1024*HID_/1024), 256, 0, stream>>>(z_w, wz_bf, 1024*HID_);
  f2bf_kernel<<<dim3(1024*HID_/1024), 256, 0, stream>>>(out_w, outw_bf, 1024*HID_);

  gemm_mfma_split_kernel<<<dim3(CONV_DIM_/128, MROWS/128), 256, 0, stream>>>(
      hs_hi, hs_lo, wc_hi, wc_lo, mixed, MROWS, CONV_DIM_, HID_);
  gemm_mfma_kernel<1><<<dim3(1024/128, MROWS/128), 256, 0, stream>>>(
      hs_hi, wz_bf, zbuf, MROWS, 1024, HID_);
  proj_ba_kernel<<<dim3(MROWS), dim3(128), 0, stream>>>(hs, b_w, a_w, dt_bias, A_log, gbuf, beta);
  conv_route_kernel<<<dim3((B_*256*CONV_DIM_)/256), dim3(256), 0, stream>>>(
      mixed, conv_w, qhi, qlo, khi, klo, vb);
  scan_ab_kernel<<<dim3(512), dim3(256), 0, stream>>>(
      qhi, qlo, khi, klo, gbuf, beta, Thi_g, Tlo_g, Bhi_g, Blo_g);
  scan_seq_kernel<<<dim3(256), dim3(512), 0, stream>>>(
      khi, klo, qhi, qlo, vb, gbuf, beta, Thi_g, Tlo_g, Bhi_g, Blo_g, ob);
  gnorm_kernel<<<dim3(32*T_), dim3(64), 0, stream>>>(ob, zbuf, norm_w, og);
  gemm_mfma_kernel<0><<<dim3(1024/128, MROWS/128), 256, 0, stream>>>(og, outw_bf, out, MROWS, 1024, HID_);
}